// Round 3
// baseline (622.361 us; speedup 1.0000x reference)
//
#include <hip/hip_runtime.h>
#include <math.h>

// Problem constants
#define B_    256
#define N_    35
#define I_    64
#define H_    256
#define ROWS  8960            // B_*N_
#define ELEMS 2293760L        // ROWS*H_

typedef __bf16 bf16x8 __attribute__((ext_vector_type(8)));
typedef float f32x4 __attribute__((ext_vector_type(4)));

struct XPtrs { const float* p[12]; };
struct GB    { const __bf16* a0[12]; const __bf16* a1[12]; const float* hp[12]; };
struct MshA  { const __bf16* oa[4]; const __bf16* ob[4]; const __bf16* oc[4];
               const float* S[4]; __bf16* com; float* accs; };

#define GLOAD_LDS16(g, l) __builtin_amdgcn_global_load_lds( \
    (const __attribute__((address_space(1))) unsigned int*)(g), \
    (__attribute__((address_space(3))) unsigned int*)(l), 16, 0, 0)

// ---------------- merged pre-work: prep (blk 0..28) + wc (blk 29..1564) + wt (blk 1565..2236) ----
__global__ void pre_kernel(const float* __restrict__ As_, const float* __restrict__ Af_,
                           const float* __restrict__ At_, float* __restrict__ A12,
                           float* __restrict__ A12sq,
                           const float* __restrict__ S0, const float* __restrict__ S1,
                           const float* __restrict__ S2, const float* __restrict__ S3,
                           float* __restrict__ l1out, float* __restrict__ accs,
                           const float* __restrict__ V1, const float* __restrict__ c1,
                           const float* __restrict__ V2, const float* __restrict__ c2,
                           __bf16* __restrict__ WcT,
                           const float* __restrict__ Wr, const float* __restrict__ Wz,
                           const float* __restrict__ Wh, __bf16* __restrict__ WT) {
    __shared__ float shf[64 * 65];        // 16.6 KB, reused by prep (3*1225) and wt (64*65)
    int blk = blockIdx.x;
    int tid = threadIdx.x;

    if (blk >= 1565) {                    // ---- wt role: GRU weight transpose ----
        int t = blk - 1565;               // 0..671
        int z = t >> 5;                   // 0..20
        int rem = t & 31;
        int bx = rem & 3, by = rem >> 2;  // grid.x=4, grid.y=8
        int mat = z / 7, gg = z % 7;
        const float* srcs[3] = {Wr, Wz, Wh};
        const float* src = srcs[mat] + (long)gg * 512 * 256;
        __bf16* dst = WT + ((long)mat * 7 + gg) * 256 * 512;
        int n0 = bx * 64;
        int k0 = by * 64;
        float (*T)[65] = (float(*)[65])shf;
        int c = tid & 63, r0 = tid >> 6;
        for (int r = r0; r < 64; r += 4)
            T[r][c] = src[(long)(k0 + r) * 256 + n0 + c];
        __syncthreads();
        for (int n = r0; n < 64; n += 4)
            dst[(long)(n0 + n) * 512 + k0 + c] = (__bf16)T[c][n];
        return;
    }
    if (blk >= 29) {                      // ---- wc role: basis-composed GCN weights ----
        int idx = (blk - 29) * 256 + tid; // 12*256*128 total
        int k = idx & 127;
        int o = (idx >> 7) & 255;
        int r = idx >> 15;
        float acc = 0.f;
        if (k < 64) {
            for (int bb = 0; bb < 4; bb++) acc += c1[r*4+bb] * V1[((long)bb*64 + k)*256 + o];
        } else {
            int kk = k - 64;
            for (int bb = 0; bb < 4; bb++) acc += c2[r*4+bb] * V2[((long)bb*64 + kk)*256 + o];
        }
        WcT[idx] = (__bf16)acc;
        return;
    }
    if (blk >= 28) {                      // ---- zero accs ----
        if (tid < 8) accs[tid] = 0.f;
        return;
    }
    if (blk >= 24) {                      // ---- L1 norms ----
        const float* mats[4] = {S0, S1, S2, S3};
        const float* S = mats[blk - 24];
        float s = 0.f;
        for (int i = tid; i < N_ * N_; i += 256) s += fabsf(S[i]);
        for (int off = 32; off > 0; off >>= 1) s += __shfl_down(s, off);
        __shared__ float wr[4];
        if ((tid & 63) == 0) wr[tid >> 6] = s;
        __syncthreads();
        if (tid == 0) l1out[blk - 24] = wr[0] + wr[1] + wr[2] + wr[3];
        return;
    }
    // ---- compose adjacencies ----
    int v = blk / 12, r = blk % 12;
    float (*M)[N_ * N_] = (float(*)[N_ * N_])shf;
    for (int i = tid; i < N_ * N_; i += 256) {
        float a = As_[i], f = Af_[i], t = At_[i];
        if (v) { a *= a; f *= f; t *= t; }
        M[0][i] = a; M[1][i] = f; M[2][i] = t;
    }
    __syncthreads();
    const int kind[12] = {0,0,0, 1,1,1,1,1,1, 2,2,2};
    const int ia[12]   = {0,1,2, 0,1,0,2,1,2, 0,0,2};
    const int ib[12]   = {0,1,2, 1,0,2,0,2,1, 1,2,0};
    const int ic[12]   = {0,0,0, 0,0,0,0,0,0, 2,1,1};
    const float* Ma = M[ia[r]];
    const float* Mb = M[ib[r]];
    const float* Mc = M[ic[r]];
    float* dst = (v ? A12sq : A12) + r * N_ * N_;
    for (int i = tid; i < N_ * N_; i += 256) {
        int m = i / N_, n = i % N_;
        float acc;
        if (kind[r] == 0) {
            acc = Ma[i];
        } else if (kind[r] == 1) {
            acc = 0.f;
            for (int p = 0; p < N_; p++) acc += Ma[m*N_+p] * Mb[p*N_+n];
        } else {
            acc = 0.f;
            for (int p = 0; p < N_; p++) {
                float t = 0.f;
                for (int q = 0; q < N_; q++) t += Mb[p*N_+q] * Mc[q*N_+n];
                acc += Ma[m*N_+p] * t;
            }
        }
        dst[i] = acc;
    }
}

// ---------------- xA fold: register-cached x, scalar(SGPR) A, pure v_fmac loop ----------------
__global__ __launch_bounds__(256)
void xa_kernel(XPtrs xp, const float* __restrict__ A12, const float* __restrict__ A12sq,
               __bf16* __restrict__ xAc) {
    int r = blockIdx.x;
    int w = __builtin_amdgcn_readfirstlane(threadIdx.x >> 6);
    int v = w & 1, bl = w >> 1;
    int lane = threadIdx.x & 63;
    int b = blockIdx.y * 2 + bl;
    const float* x = xp.p[r] + (long)b * (N_ * I_);
    const float* As = (v ? A12sq : A12) + r * (N_ * N_);
    float xv[N_];
#pragma unroll
    for (int n = 0; n < N_; n++) xv[n] = x[n * I_ + lane];
    float acc[N_];
#pragma unroll
    for (int m = 0; m < N_; m++) acc[m] = 0.f;
#pragma unroll
    for (int n = 0; n < N_; n++) {
#pragma unroll
        for (int m = 0; m < N_; m++) acc[m] += As[m * N_ + n] * xv[n];
    }
    long obase = ((long)r * ROWS + (long)b * N_) * 128 + v * 64 + lane;
#pragma unroll
    for (int m = 0; m < N_; m++) xAc[obase + (long)m * 128] = (__bf16)acc[m];
}

// ---------------- bf16 MFMA GEMM (GCN), 128x128 tile, conflict-free chunked LDS ----
template<int ACT>
__global__ __launch_bounds__(256)
void gemm_bf16(GB gb, int K0, int K, int lda0, int lda1,
               const __bf16* __restrict__ B0, const __bf16* __restrict__ B1,
               int N0, int ldb, long bstr,
               void* __restrict__ Cp, int ldc, long cstr,
               const __bf16* __restrict__ Zb, long zstr) {
    int bz = blockIdx.z;
    int n0 = blockIdx.x * 128;
    int m0 = blockIdx.y * 128;
    const __bf16* a0 = gb.a0[bz];
    const __bf16* a1 = gb.a1[bz];
    const __bf16* bbase = ((n0 < N0) ? B0 : B1) + bz * bstr;
    int nloc = (n0 < N0) ? n0 : (n0 - N0);
    __shared__ __bf16 As[2][8 * 512];   // 2 x 8KB
    __shared__ __bf16 Bs[2][8 * 512];   // 2 x 8KB
    int tid = threadIdx.x;
    int lane = tid & 63;
    int w = tid >> 6;
    int wm = (w & 1) * 64, wn = (w >> 1) * 64;
    int l15 = lane & 15, q = lane >> 4;
    int kq8 = q * 8;
    int ca = (w & 1) * 4;
    int cb = (w >> 1) * 4;
    f32x4 acc[4][4] = {};
    f32x4 accA[4][4];
    int ksplit = K >> 1;

    auto stage = [&](int buf, int kt2) {
        const __bf16* aseg; int kk; int lda;
        if (kt2 < K0) { aseg = a0; kk = kt2; lda = lda0; }
        else          { aseg = a1; kk = kt2 - K0; lda = lda1; }
        GLOAD_LDS16(aseg + (long)(m0 + w * 16 + l15) * lda + kk + kq8,      &As[buf][w * 512]);
        GLOAD_LDS16(aseg + (long)(m0 + 64 + w * 16 + l15) * lda + kk + kq8, &As[buf][(4 + w) * 512]);
        GLOAD_LDS16(bbase + (long)(nloc + w * 16 + l15) * ldb + kt2 + kq8,      &Bs[buf][w * 512]);
        GLOAD_LDS16(bbase + (long)(nloc + 64 + w * 16 + l15) * ldb + kt2 + kq8, &Bs[buf][(4 + w) * 512]);
    };

    stage(0, 0);
    int cur = 0;
    for (int kt = 0; kt < K; kt += 32) {
        __syncthreads();
        if (kt + 32 < K) stage(cur ^ 1, kt + 32);
        const __bf16* Ac = As[cur];
        const __bf16* Bc = Bs[cur];
        bf16x8 af[4], bfr[4];
#pragma unroll
        for (int mt = 0; mt < 4; mt++) af[mt]  = *(const bf16x8*)(Ac + (ca + mt) * 512 + q * 128 + l15 * 8);
#pragma unroll
        for (int nt = 0; nt < 4; nt++) bfr[nt] = *(const bf16x8*)(Bc + (cb + nt) * 512 + q * 128 + l15 * 8);
#pragma unroll
        for (int mt = 0; mt < 4; mt++)
#pragma unroll
            for (int nt = 0; nt < 4; nt++)
                acc[mt][nt] = __builtin_amdgcn_mfma_f32_16x16x32_bf16(af[mt], bfr[nt], acc[mt][nt], 0, 0, 0);
        if (ACT == 4 && (kt + 32) == ksplit) {
#pragma unroll
            for (int mt = 0; mt < 4; mt++)
#pragma unroll
                for (int nt = 0; nt < 4; nt++)
#pragma unroll
                    for (int r = 0; r < 4; r++) {
                        accA[mt][nt][r] = fmaxf(acc[mt][nt][r], 0.f);
                        acc[mt][nt][r] = 0.f;
                    }
        }
        cur ^= 1;
    }

#pragma unroll
    for (int mt = 0; mt < 4; mt++) {
#pragma unroll
        for (int nt = 0; nt < 4; nt++) {
#pragma unroll
            for (int r = 0; r < 4; r++) {
                long row = m0 + wm + mt*16 + q*4 + r;
                int col  = n0 + wn + nt*16 + l15;
                float vv = acc[mt][nt][r];
                ((__bf16*)Cp)[bz*cstr + row * ldc + col] = (__bf16)(accA[mt][nt][r] + fmaxf(vv, 0.f));
            }
        }
    }
}

// ---------------- fused GRU v2: direct-to-register A, 8 waves, 32KB LDS, 1 barrier ----------
// Per block: 32 rows, one g. Phase 1: gates (8 waves x 64 cols). Epilogue1 -> RH/ZB in LDS.
// Phase 2a: o-part of hh (pre-barrier). Barrier. Phase 2b: rh-part. GRU epilogue.
// LDS (bf16 elems): RH chunked [0,8192), ZB row-major [8192,16384).
__global__ __launch_bounds__(512, 4)
void gru_fused(GB gb, const __bf16* __restrict__ WT, float* __restrict__ outp) {
    __shared__ __bf16 sm[16384];     // 32 KB
    int g = blockIdx.y;
    int m0 = blockIdx.x * 32;
    int tid = threadIdx.x;
    int lane = tid & 63;
    int w = tid >> 6;                // 0..7
    int l15 = lane & 15, q = lane >> 4;
    int w4 = w & 3;
    const float* __restrict__ hpg = gb.hp[g];
    const __bf16* __restrict__ ob = gb.a0[g];

    // ---- phase 1: gates = [o|h] @ [Wr|Wz]; waves 0-3 -> r (Wr), 4-7 -> z (Wz) ----
    const __bf16* wrz = WT + ((w < 4) ? (long)g : (long)(7 + g)) * 131072;
    const __bf16* b1base = wrz + (long)(w4 * 64 + l15) * 512 + q * 8;

    bf16x8 bA[4], bB[4], aA[2], aB[2];
    f32x4 acc[2][4] = {};

    auto loadB1 = [&](bf16x8* d, int s) {
#pragma unroll
        for (int nt = 0; nt < 4; nt++)
            d[nt] = *(const bf16x8*)(b1base + nt * 8192 + s * 32);
    };
    auto loadA1 = [&](bf16x8* d, int s) {
        if (s < 8) {
#pragma unroll
            for (int mt = 0; mt < 2; mt++)
                d[mt] = *(const bf16x8*)(ob + (long)(m0 + mt * 16 + l15) * 256 + s * 32 + q * 8);
        } else {
#pragma unroll
            for (int mt = 0; mt < 2; mt++) {
                const float* hs = hpg + (long)(m0 + mt * 16 + l15) * 256 + (s - 8) * 32 + q * 8;
                float4 u0 = *(const float4*)hs;
                float4 u1 = *(const float4*)(hs + 4);
                bf16x8 t;
                t[0] = (__bf16)u0.x; t[1] = (__bf16)u0.y; t[2] = (__bf16)u0.z; t[3] = (__bf16)u0.w;
                t[4] = (__bf16)u1.x; t[5] = (__bf16)u1.y; t[6] = (__bf16)u1.z; t[7] = (__bf16)u1.w;
                d[mt] = t;
            }
        }
    };

    loadB1(bA, 0); loadA1(aA, 0);
    loadB1(bB, 1); loadA1(aB, 1);
#pragma unroll
    for (int s = 0; s < 16; s += 2) {
#pragma unroll
        for (int mt = 0; mt < 2; mt++)
#pragma unroll
            for (int nt = 0; nt < 4; nt++)
                acc[mt][nt] = __builtin_amdgcn_mfma_f32_16x16x32_bf16(aA[mt], bA[nt], acc[mt][nt], 0, 0, 0);
        if (s + 2 < 16) { loadB1(bA, s + 2); loadA1(aA, s + 2); }
#pragma unroll
        for (int mt = 0; mt < 2; mt++)
#pragma unroll
            for (int nt = 0; nt < 4; nt++)
                acc[mt][nt] = __builtin_amdgcn_mfma_f32_16x16x32_bf16(aB[mt], bB[nt], acc[mt][nt], 0, 0, 0);
        if (s + 3 < 16) { loadB1(bB, s + 3); loadA1(aB, s + 3); }
    }

    // ---- epilogue 1: waves 0-3 -> RH = sigmoid(r)*h (chunked); waves 4-7 -> ZB = sigmoid(z) ----
    if (w < 4) {
#pragma unroll
        for (int mt = 0; mt < 2; mt++)
#pragma unroll
            for (int nt = 0; nt < 4; nt++)
#pragma unroll
                for (int j = 0; j < 4; j++) {
                    int row = mt * 16 + q * 4 + j;
                    int colg = w4 * 64 + nt * 16 + l15;
                    float rv = __builtin_amdgcn_rcpf(1.f + __expf(-acc[mt][nt][j]));
                    float hb = hpg[(long)(m0 + row) * 256 + colg];
                    int rhoff = ((w4 * 2 + (nt >> 1)) * 2 + mt) * 512
                              + ((nt & 1) * 2 + (l15 >> 3)) * 128 + (q * 4 + j) * 8 + (l15 & 7);
                    sm[rhoff] = (__bf16)(rv * hb);
                }
    } else {
#pragma unroll
        for (int mt = 0; mt < 2; mt++)
#pragma unroll
            for (int nt = 0; nt < 4; nt++)
#pragma unroll
                for (int j = 0; j < 4; j++) {
                    int row = mt * 16 + q * 4 + j;
                    int colp = w4 * 64 + nt * 16 + l15;
                    float zv = __builtin_amdgcn_rcpf(1.f + __expf(-acc[mt][nt][j]));
                    sm[8192 + row * 256 + colp] = (__bf16)zv;
                }
    }

    // ---- phase 2a: o-part of hh = [rh|o]@Wh (k 256..511) — no barrier dependency ----
    const __bf16* wh = WT + (long)(14 + g) * 131072;
    const __bf16* b2base = wh + (long)(w * 32 + l15) * 512 + q * 8;
    f32x4 acc2[2][2] = {};
    bf16x8 cA[2], cB[2];

    auto loadB2o = [&](bf16x8* d, int s8) {
#pragma unroll
        for (int nt = 0; nt < 2; nt++)
            d[nt] = *(const bf16x8*)(b2base + nt * 8192 + 256 + s8 * 32);
    };
    auto loadA2o = [&](bf16x8* d, int s8) {
#pragma unroll
        for (int mt = 0; mt < 2; mt++)
            d[mt] = *(const bf16x8*)(ob + (long)(m0 + mt * 16 + l15) * 256 + s8 * 32 + q * 8);
    };

    loadB2o(cA, 0); loadA2o(aA, 0);
    loadB2o(cB, 1); loadA2o(aB, 1);
#pragma unroll
    for (int s = 0; s < 8; s += 2) {
#pragma unroll
        for (int mt = 0; mt < 2; mt++)
#pragma unroll
            for (int nt = 0; nt < 2; nt++)
                acc2[mt][nt] = __builtin_amdgcn_mfma_f32_16x16x32_bf16(aA[mt], cA[nt], acc2[mt][nt], 0, 0, 0);
        if (s + 2 < 8) { loadB2o(cA, s + 2); loadA2o(aA, s + 2); }
#pragma unroll
        for (int mt = 0; mt < 2; mt++)
#pragma unroll
            for (int nt = 0; nt < 2; nt++)
                acc2[mt][nt] = __builtin_amdgcn_mfma_f32_16x16x32_bf16(aB[mt], cB[nt], acc2[mt][nt], 0, 0, 0);
        if (s + 3 < 8) { loadB2o(cB, s + 3); loadA2o(aB, s + 3); }
    }

    __syncthreads();                 // RH/ZB visible to all waves

    // ---- phase 2b: rh-part (k 0..255): A from LDS chunks, B 2-deep from global ----
    auto loadB2r = [&](bf16x8* d, int s8) {
#pragma unroll
        for (int nt = 0; nt < 2; nt++)
            d[nt] = *(const bf16x8*)(b2base + nt * 8192 + s8 * 32);
    };
    loadB2r(cA, 0);
    loadB2r(cB, 1);
#pragma unroll
    for (int s = 0; s < 8; s += 2) {
        bf16x8 ar[2];
#pragma unroll
        for (int mt = 0; mt < 2; mt++)
            ar[mt] = *(const bf16x8*)(&sm[(s * 2 + mt) * 512 + q * 128 + l15 * 8]);
#pragma unroll
        for (int mt = 0; mt < 2; mt++)
#pragma unroll
            for (int nt = 0; nt < 2; nt++)
                acc2[mt][nt] = __builtin_amdgcn_mfma_f32_16x16x32_bf16(ar[mt], cA[nt], acc2[mt][nt], 0, 0, 0);
        if (s + 2 < 8) loadB2r(cA, s + 2);
#pragma unroll
        for (int mt = 0; mt < 2; mt++)
            ar[mt] = *(const bf16x8*)(&sm[((s + 1) * 2 + mt) * 512 + q * 128 + l15 * 8]);
#pragma unroll
        for (int mt = 0; mt < 2; mt++)
#pragma unroll
            for (int nt = 0; nt < 2; nt++)
                acc2[mt][nt] = __builtin_amdgcn_mfma_f32_16x16x32_bf16(ar[mt], cB[nt], acc2[mt][nt], 0, 0, 0);
        if (s + 3 < 8) loadB2r(cB, s + 3);
    }

    // ---- GRU epilogue: out = (1-z)*h + z*tanh(hh) ----
    float* og = outp + (long)g * ELEMS;
#pragma unroll
    for (int mt = 0; mt < 2; mt++)
#pragma unroll
        for (int nt = 0; nt < 2; nt++)
#pragma unroll
            for (int j = 0; j < 4; j++) {
                int row = mt * 16 + q * 4 + j;
                int col = w * 32 + nt * 16 + l15;
                float zz = (float)sm[8192 + row * 256 + col];
                float e = __expf(2.f * acc2[mt][nt][j]);
                float th = 1.f - 2.f * __builtin_amdgcn_rcpf(e + 1.f);
                float hv = hpg[(long)(m0 + row) * 256 + col];
                og[(long)(m0 + row) * 256 + col] = (1.f - zz) * hv + zz * th;
            }
}

// ---------------- msh + sim + com: register-cached o, scalar S, pure v_fmac ----------------
__global__ __launch_bounds__(256, 1)
void msh_kernel(MshA ma) {
    int z = blockIdx.z;
    bool tri = (z == 3);
    int b = blockIdx.x;
    int h0 = blockIdx.y * 64;
    int lane = threadIdx.x & 63;
    int w = __builtin_amdgcn_readfirstlane(threadIdx.x >> 6);
    long base = (long)b * N_ * H_ + h0 + lane;
    const __bf16* pa = ma.oa[z] + base;
    const __bf16* pb = ma.ob[z] + base;
    const __bf16* pc = ma.oc[z] + base;
    float av[N_], bv[N_], cv[N_];
#pragma unroll
    for (int n = 0; n < N_; n++) {
        av[n] = (float)pa[n * H_];
        bv[n] = (float)pb[n * H_];
    }
    if (tri) {
#pragma unroll
        for (int n = 0; n < N_; n++) cv[n] = (float)pc[n * H_];
    }
    const float* S = ma.S[z];
    __bf16* com = ma.com + (long)z * ELEMS + base;
    float lsum = 0.f;
    for (int mm = w; mm < N_; mm += 4) {        // mm wave-uniform
        float a = 0.f, bb = 0.f, cc = 0.f;
#pragma unroll
        for (int n = 0; n < N_; n++) {
            float s = S[n * N_ + mm];           // uniform -> s_load
            a += av[n] * s;
            bb += bv[n] * s;
            if (tri) cc += cv[n] * s;
        }
        if (tri) {
            com[(long)mm * H_] = (__bf16)((a + bb + cc) * (1.f/3.f));
            float d1 = a - bb, d2 = a - cc, d3 = bb - cc;
            lsum += d1*d1 + d2*d2 + d3*d3;
        } else {
            com[(long)mm * H_] = (__bf16)(0.5f * (a + bb));
            float d = a - bb;
            lsum += d * d;
        }
    }
    for (int off = 32; off > 0; off >>= 1) lsum += __shfl_down(lsum, off);
    __shared__ float wred[4];
    if (lane == 0) wred[w] = lsum;
    __syncthreads();
    if (threadIdx.x == 0) atomicAdd(ma.accs + z, wred[0] + wred[1] + wred[2] + wred[3]);
}

// ---------------- finalize sims ----------------
__global__ void fin_kernel(const float* __restrict__ accs, float* __restrict__ outp) {
    if (threadIdx.x == 0) {
        float inv = 1.f / 2293760.f;
        outp[0] = accs[0] * inv;
        outp[1] = accs[1] * inv;
        outp[2] = accs[2] * inv;
        outp[3] = accs[3] * inv;
    }
}

extern "C" void kernel_launch(void* const* d_in, const int* in_sizes, int n_in,
                              void* d_out, int out_size, void* d_ws, size_t ws_size,
                              hipStream_t stream) {
    const float* const* in = (const float* const*)d_in;
    float* out = (float*)d_out;
    char* ws = (char*)d_ws;

    size_t off = 0;
    auto alloc = [&](size_t bytes) { size_t o = off; off += (bytes + 255) & ~(size_t)255; return o; };
    float*  A12   = (float*)(ws + alloc(12*N_*N_*4));
    float*  A12sq = (float*)(ws + alloc(12*N_*N_*4));
    __bf16* WcT   = (__bf16*)(ws + alloc((size_t)12*256*128*2));
    __bf16* WT    = (__bf16*)(ws + alloc((size_t)21*256*512*2));
    float*  accs  = (float*)(ws + alloc(256));
    __bf16* gout  = (__bf16*)(ws + alloc((size_t)12*ELEMS*2));
    __bf16* com   = (__bf16*)(ws + alloc((size_t)4*ELEMS*2));
    __bf16* xAc   = (__bf16*)(ws + alloc((size_t)12*ROWS*128*2));

    XPtrs xp;
    for (int i = 0; i < 12; i++) xp.p[i] = in[i];

    // merged prep + wc + wt  (29 + 1536 + 672 blocks)
    pre_kernel<<<2237, 256, 0, stream>>>(in[12], in[13], in[14], A12, A12sq,
                                         in[27], in[26], in[28], in[29],
                                         out + 7L*ELEMS + 4, accs,
                                         in[22], in[23], in[24], in[25], WcT,
                                         in[30], in[31], in[32], WT);
    xa_kernel<<<dim3(12, 128), 256, 0, stream>>>(xp, A12, A12sq, xAc);

    // GCN: gout[r] = relu(xA1@W1) + relu(xA2@W2)  (ACT=4 split-relu at K/2=64)
    {
        GB gb{};
        for (int z = 0; z < 12; z++) { gb.a0[z] = xAc + (long)z*ROWS*128; gb.a1[z] = gb.a0[z]; }
        gemm_bf16<4><<<dim3(2, 70, 12), 256, 0, stream>>>(
            gb, 128, 128, 128, 128,
            WcT, WcT, 256, 128, 32768L,
            gout, 256, ELEMS, (const __bf16*)nullptr, 0L);
    }

    // msh + sim + com (4 batched in z)
    {
        MshA ma{};
        ma.oa[0] = gout + 3L*ELEMS; ma.ob[0] = gout + 4L*ELEMS; ma.oc[0] = ma.oa[0];
        ma.oa[1] = gout + 5L*ELEMS; ma.ob[1] = gout + 6L*ELEMS; ma.oc[1] = ma.oa[1];
        ma.oa[2] = gout + 7L*ELEMS; ma.ob[2] = gout + 8L*ELEMS; ma.oc[2] = ma.oa[2];
        ma.oa[3] = gout + 9L*ELEMS; ma.ob[3] = gout + 10L*ELEMS; ma.oc[3] = gout + 11L*ELEMS;
        ma.S[0] = in[26]; ma.S[1] = in[27]; ma.S[2] = in[28]; ma.S[3] = in[29];
        ma.com = com; ma.accs = accs;
        msh_kernel<<<dim3(256, 4, 4), 256, 0, stream>>>(ma);
    }

    fin_kernel<<<1, 64, 0, stream>>>(accs, out + 7L*ELEMS);

    // Fused GRU v2: direct-A, fp32-h inline convert, 8 waves, 32KB LDS
    {
        GB gb{};
        for (int g = 0; g < 7; g++) {
            gb.a0[g] = (g < 3) ? gout + (long)g*ELEMS : com + (long)(g - 3)*ELEMS;
            gb.hp[g] = in[15 + g];
        }
        gru_fused<<<dim3(280, 7), 512, 0, stream>>>(gb, WT, out);
    }
}

// Round 4
// 558.217 us; speedup vs baseline: 1.1149x; 1.1149x over previous
//
#include <hip/hip_runtime.h>
#include <math.h>

// Problem constants
#define B_    256
#define N_    35
#define I_    64
#define H_    256
#define ROWS  8960            // B_*N_
#define ELEMS 2293760L        // ROWS*H_

typedef __bf16 bf16x8 __attribute__((ext_vector_type(8)));
typedef float f32x4 __attribute__((ext_vector_type(4)));

struct XPtrs { const float* p[12]; };
struct HPtrs { const float* p[7]; };
struct GB    { const __bf16* a0[12]; const __bf16* a1[12]; const float* hp[12]; };
struct MshA  { const __bf16* oa[4]; const __bf16* ob[4]; const __bf16* oc[4];
               const float* S[4]; __bf16* com; float* accs; };

#define GLOAD_LDS16(g, l) __builtin_amdgcn_global_load_lds( \
    (const __attribute__((address_space(1))) unsigned int*)(g), \
    (__attribute__((address_space(3))) unsigned int*)(l), 16, 0, 0)

// ---------------- merged pre-work:
//   blk 0..23    compose adjacencies
//   blk 24..27   L1 norms
//   blk 28       zero accs
//   blk 29..1564 wc (GCN basis weights)
//   blk 1565..2236 wt (GRU weight transpose)
//   blk 2237..17916 hcast (hidden fp32 -> bf16)
__global__ void pre_kernel(const float* __restrict__ As_, const float* __restrict__ Af_,
                           const float* __restrict__ At_, float* __restrict__ A12,
                           float* __restrict__ A12sq,
                           const float* __restrict__ S0, const float* __restrict__ S1,
                           const float* __restrict__ S2, const float* __restrict__ S3,
                           float* __restrict__ l1out, float* __restrict__ accs,
                           const float* __restrict__ V1, const float* __restrict__ c1,
                           const float* __restrict__ V2, const float* __restrict__ c2,
                           __bf16* __restrict__ WcT,
                           const float* __restrict__ Wr, const float* __restrict__ Wz,
                           const float* __restrict__ Wh, __bf16* __restrict__ WT,
                           HPtrs hp, __bf16* __restrict__ hbf) {
    __shared__ float shf[64 * 65];        // 16.6 KB, reused by prep and wt roles
    int blk = blockIdx.x;
    int tid = threadIdx.x;

    if (blk >= 2237) {                    // ---- hcast role ----
        int t = blk - 2237;               // 0..15679
        int gg = t / 2240;
        int bx = t - gg * 2240;
        long idx = ((long)bx * 256 + tid) * 4;
        float4 v = *(const float4*)(hp.p[gg] + idx);
        __bf16* o = hbf + (long)gg * ELEMS + idx;
        o[0] = (__bf16)v.x; o[1] = (__bf16)v.y; o[2] = (__bf16)v.z; o[3] = (__bf16)v.w;
        return;
    }
    if (blk >= 1565) {                    // ---- wt role: GRU weight transpose ----
        int t = blk - 1565;               // 0..671
        int z = t >> 5;                   // 0..20
        int rem = t & 31;
        int bx = rem & 3, by = rem >> 2;
        int mat = z / 7, gg = z % 7;
        const float* srcs[3] = {Wr, Wz, Wh};
        const float* src = srcs[mat] + (long)gg * 512 * 256;
        __bf16* dst = WT + ((long)mat * 7 + gg) * 256 * 512;
        int n0 = bx * 64;
        int k0 = by * 64;
        float (*T)[65] = (float(*)[65])shf;
        int c = tid & 63, r0 = tid >> 6;
        for (int r = r0; r < 64; r += 4)
            T[r][c] = src[(long)(k0 + r) * 256 + n0 + c];
        __syncthreads();
        for (int n = r0; n < 64; n += 4)
            dst[(long)(n0 + n) * 512 + k0 + c] = (__bf16)T[c][n];
        return;
    }
    if (blk >= 29) {                      // ---- wc role ----
        int idx = (blk - 29) * 256 + tid;
        int k = idx & 127;
        int o = (idx >> 7) & 255;
        int r = idx >> 15;
        float acc = 0.f;
        if (k < 64) {
            for (int bb = 0; bb < 4; bb++) acc += c1[r*4+bb] * V1[((long)bb*64 + k)*256 + o];
        } else {
            int kk = k - 64;
            for (int bb = 0; bb < 4; bb++) acc += c2[r*4+bb] * V2[((long)bb*64 + kk)*256 + o];
        }
        WcT[idx] = (__bf16)acc;
        return;
    }
    if (blk >= 28) {
        if (tid < 8) accs[tid] = 0.f;
        return;
    }
    if (blk >= 24) {                      // ---- L1 norms ----
        const float* mats[4] = {S0, S1, S2, S3};
        const float* S = mats[blk - 24];
        float s = 0.f;
        for (int i = tid; i < N_ * N_; i += 256) s += fabsf(S[i]);
        for (int off = 32; off > 0; off >>= 1) s += __shfl_down(s, off);
        __shared__ float wr[4];
        if ((tid & 63) == 0) wr[tid >> 6] = s;
        __syncthreads();
        if (tid == 0) l1out[blk - 24] = wr[0] + wr[1] + wr[2] + wr[3];
        return;
    }
    // ---- compose adjacencies ----
    int v = blk / 12, r = blk % 12;
    float (*M)[N_ * N_] = (float(*)[N_ * N_])shf;
    for (int i = tid; i < N_ * N_; i += 256) {
        float a = As_[i], f = Af_[i], t = At_[i];
        if (v) { a *= a; f *= f; t *= t; }
        M[0][i] = a; M[1][i] = f; M[2][i] = t;
    }
    __syncthreads();
    const int kind[12] = {0,0,0, 1,1,1,1,1,1, 2,2,2};
    const int ia[12]   = {0,1,2, 0,1,0,2,1,2, 0,0,2};
    const int ib[12]   = {0,1,2, 1,0,2,0,2,1, 1,2,0};
    const int ic[12]   = {0,0,0, 0,0,0,0,0,0, 2,1,1};
    const float* Ma = M[ia[r]];
    const float* Mb = M[ib[r]];
    const float* Mc = M[ic[r]];
    float* dst = (v ? A12sq : A12) + r * N_ * N_;
    for (int i = tid; i < N_ * N_; i += 256) {
        int m = i / N_, n = i % N_;
        float acc;
        if (kind[r] == 0) {
            acc = Ma[i];
        } else if (kind[r] == 1) {
            acc = 0.f;
            for (int p = 0; p < N_; p++) acc += Ma[m*N_+p] * Mb[p*N_+n];
        } else {
            acc = 0.f;
            for (int p = 0; p < N_; p++) {
                float t = 0.f;
                for (int q = 0; q < N_; q++) t += Mb[p*N_+q] * Mc[q*N_+n];
                acc += Ma[m*N_+p] * t;
            }
        }
        dst[i] = acc;
    }
}

// ---------------- xA fold ----------------
__global__ __launch_bounds__(256)
void xa_kernel(XPtrs xp, const float* __restrict__ A12, const float* __restrict__ A12sq,
               __bf16* __restrict__ xAc) {
    int r = blockIdx.x;
    int w = __builtin_amdgcn_readfirstlane(threadIdx.x >> 6);
    int v = w & 1, bl = w >> 1;
    int lane = threadIdx.x & 63;
    int b = blockIdx.y * 2 + bl;
    const float* x = xp.p[r] + (long)b * (N_ * I_);
    const float* As = (v ? A12sq : A12) + r * (N_ * N_);
    float xv[N_];
#pragma unroll
    for (int n = 0; n < N_; n++) xv[n] = x[n * I_ + lane];
    float acc[N_];
#pragma unroll
    for (int m = 0; m < N_; m++) acc[m] = 0.f;
#pragma unroll
    for (int n = 0; n < N_; n++) {
#pragma unroll
        for (int m = 0; m < N_; m++) acc[m] += As[m * N_ + n] * xv[n];
    }
    long obase = ((long)r * ROWS + (long)b * N_) * 128 + v * 64 + lane;
#pragma unroll
    for (int m = 0; m < N_; m++) xAc[obase + (long)m * 128] = (__bf16)acc[m];
}

// ---------------- bf16 MFMA GEMM (GCN), 128x128 tile, conflict-free chunked LDS ----
template<int ACT>
__global__ __launch_bounds__(256)
void gemm_bf16(GB gb, int K0, int K, int lda0, int lda1,
               const __bf16* __restrict__ B0, const __bf16* __restrict__ B1,
               int N0, int ldb, long bstr,
               void* __restrict__ Cp, int ldc, long cstr,
               const __bf16* __restrict__ Zb, long zstr) {
    int bz = blockIdx.z;
    int n0 = blockIdx.x * 128;
    int m0 = blockIdx.y * 128;
    const __bf16* a0 = gb.a0[bz];
    const __bf16* a1 = gb.a1[bz];
    const __bf16* bbase = ((n0 < N0) ? B0 : B1) + bz * bstr;
    int nloc = (n0 < N0) ? n0 : (n0 - N0);
    __shared__ __bf16 As[2][8 * 512];
    __shared__ __bf16 Bs[2][8 * 512];
    int tid = threadIdx.x;
    int lane = tid & 63;
    int w = tid >> 6;
    int wm = (w & 1) * 64, wn = (w >> 1) * 64;
    int l15 = lane & 15, q = lane >> 4;
    int kq8 = q * 8;
    int ca = (w & 1) * 4;
    int cb = (w >> 1) * 4;
    f32x4 acc[4][4] = {};
    f32x4 accA[4][4];
    int ksplit = K >> 1;

    auto stage = [&](int buf, int kt2) {
        const __bf16* aseg; int kk; int lda;
        if (kt2 < K0) { aseg = a0; kk = kt2; lda = lda0; }
        else          { aseg = a1; kk = kt2 - K0; lda = lda1; }
        GLOAD_LDS16(aseg + (long)(m0 + w * 16 + l15) * lda + kk + kq8,      &As[buf][w * 512]);
        GLOAD_LDS16(aseg + (long)(m0 + 64 + w * 16 + l15) * lda + kk + kq8, &As[buf][(4 + w) * 512]);
        GLOAD_LDS16(bbase + (long)(nloc + w * 16 + l15) * ldb + kt2 + kq8,      &Bs[buf][w * 512]);
        GLOAD_LDS16(bbase + (long)(nloc + 64 + w * 16 + l15) * ldb + kt2 + kq8, &Bs[buf][(4 + w) * 512]);
    };

    stage(0, 0);
    int cur = 0;
    for (int kt = 0; kt < K; kt += 32) {
        __syncthreads();
        if (kt + 32 < K) stage(cur ^ 1, kt + 32);
        const __bf16* Ac = As[cur];
        const __bf16* Bc = Bs[cur];
        bf16x8 af[4], bfr[4];
#pragma unroll
        for (int mt = 0; mt < 4; mt++) af[mt]  = *(const bf16x8*)(Ac + (ca + mt) * 512 + q * 128 + l15 * 8);
#pragma unroll
        for (int nt = 0; nt < 4; nt++) bfr[nt] = *(const bf16x8*)(Bc + (cb + nt) * 512 + q * 128 + l15 * 8);
#pragma unroll
        for (int mt = 0; mt < 4; mt++)
#pragma unroll
            for (int nt = 0; nt < 4; nt++)
                acc[mt][nt] = __builtin_amdgcn_mfma_f32_16x16x32_bf16(af[mt], bfr[nt], acc[mt][nt], 0, 0, 0);
        if (ACT == 4 && (kt + 32) == ksplit) {
#pragma unroll
            for (int mt = 0; mt < 4; mt++)
#pragma unroll
                for (int nt = 0; nt < 4; nt++)
#pragma unroll
                    for (int r = 0; r < 4; r++) {
                        accA[mt][nt][r] = fmaxf(acc[mt][nt][r], 0.f);
                        acc[mt][nt][r] = 0.f;
                    }
        }
        cur ^= 1;
    }

#pragma unroll
    for (int mt = 0; mt < 4; mt++) {
#pragma unroll
        for (int nt = 0; nt < 4; nt++) {
#pragma unroll
            for (int r = 0; r < 4; r++) {
                long row = m0 + wm + mt*16 + q*4 + r;
                int col  = n0 + wn + nt*16 + l15;
                float vv = acc[mt][nt][r];
                ((__bf16*)Cp)[bz*cstr + row * ldc + col] = (__bf16)(accA[mt][nt][r] + fmaxf(vv, 0.f));
            }
        }
    }
}

// ---------------- fused GRU v3: v1 structure + XCD-chunked swizzle + 3-deep B prefetch ----
// Per block: 32 rows, one g, 4 waves. A=[o|h] staged once to chunked LDS.
// LDS map (bf16 elems): A1c [0,16384), RH [16384,24576), ZB [24576,32768).
#define RHB 16384
#define ZBB 24576
__global__ __launch_bounds__(256, 2)
void gru_fused(GB gb, const __bf16* __restrict__ WT, float* __restrict__ outp, int gbase) {
    __shared__ __bf16 sm[32768];     // 64 KB
    // XCD-chunked bijective swizzle: gridDim.x divisible by 8; each XCD gets a
    // contiguous g-major chunk -> per-XCD L2 holds ~one g's weights (768 KB < 4 MB).
    int chunk = gridDim.x >> 3;
    int wg = blockIdx.x;
    int sw = (wg & 7) * chunk + (wg >> 3);
    int g = gbase + sw / 280;
    int m0 = (sw % 280) * 32;
    int tid = threadIdx.x;
    int lane = tid & 63;
    int w = tid >> 6;                // 0..3
    int l15 = lane & 15, q = lane >> 4;
    const float* __restrict__ hpg = gb.hp[g];

    // ---- stage A1 = [o | h] (32 rows x 512 k) into chunked LDS ----
    {
        const __bf16* src = (w < 2) ? gb.a0[g] : gb.a1[g];
#pragma unroll
        for (int i = 0; i < 8; i++) {
            int c = w * 8 + i;
            int ck = c >> 1, cr = c & 1;
            GLOAD_LDS16(src + (long)(m0 + cr * 16 + l15) * 256 + (ck & 7) * 32 + q * 8,
                        &sm[c * 512]);
        }
    }

    // ---- phase 1: gates = A1 @ [Wr|Wz]; waves 0,1 -> r (Wr), 2,3 -> z (Wz) ----
    const __bf16* wrz = WT + ((w < 2) ? (long)g : (long)(7 + g)) * 131072;
    const __bf16* b1base = wrz + (long)((w & 1) * 128 + l15) * 512 + q * 8;
    auto loadB1 = [&](bf16x8 (&d)[8], int s) {
#pragma unroll
        for (int nt = 0; nt < 8; nt++)
            d[nt] = *(const bf16x8*)(b1base + nt * 8192 + s * 32);
    };
    f32x4 acc[2][8] = {};
    auto step1 = [&](bf16x8 (&bu)[8], int s) {
        bf16x8 af[2];
#pragma unroll
        for (int mt = 0; mt < 2; mt++)
            af[mt] = *(const bf16x8*)(&sm[(s * 2 + mt) * 512 + q * 128 + l15 * 8]);
#pragma unroll
        for (int mt = 0; mt < 2; mt++)
#pragma unroll
            for (int nt = 0; nt < 8; nt++)
                acc[mt][nt] = __builtin_amdgcn_mfma_f32_16x16x32_bf16(af[mt], bu[nt], acc[mt][nt], 0, 0, 0);
        if (s + 3 < 16) loadB1(bu, s + 3);
    };

    bf16x8 bb0[8], bb1[8], bb2[8];
    loadB1(bb0, 0); loadB1(bb1, 1); loadB1(bb2, 2);
    __syncthreads();                 // A1c resident (drains prefetches too)
#pragma unroll
    for (int s = 0; s < 16; s += 3) {
        step1(bb0, s);
        if (s + 1 < 16) step1(bb1, s + 1);
        if (s + 2 < 16) step1(bb2, s + 2);
    }

    // ---- epilogue 1: waves 0,1 -> RH = sigmoid(r)*h (chunked); waves 2,3 -> ZB = sigmoid(z) ----
    if (w < 2) {
#pragma unroll
        for (int mt = 0; mt < 2; mt++)
#pragma unroll
            for (int nt = 0; nt < 8; nt++)
#pragma unroll
                for (int j = 0; j < 4; j++) {
                    int row = mt * 16 + q * 4 + j;
                    int colg = w * 128 + nt * 16 + l15;
                    float rv = __builtin_amdgcn_rcpf(1.f + __expf(-acc[mt][nt][j]));
                    float hb = hpg[(long)(m0 + row) * 256 + colg];
                    int rhoff = RHB + ((w * 4 + (nt >> 1)) * 2 + mt) * 512
                              + ((nt * 2 + (l15 >> 3)) & 3) * 128 + (q * 4 + j) * 8 + (l15 & 7);
                    sm[rhoff] = (__bf16)(rv * hb);
                }
    } else {
#pragma unroll
        for (int mt = 0; mt < 2; mt++)
#pragma unroll
            for (int nt = 0; nt < 8; nt++)
#pragma unroll
                for (int j = 0; j < 4; j++) {
                    int row = mt * 16 + q * 4 + j;
                    int colp = (w - 2) * 128 + nt * 16 + l15;
                    float zv = __builtin_amdgcn_rcpf(1.f + __expf(-acc[mt][nt][j]));
                    sm[ZBB + row * 256 + colp] = (__bf16)zv;
                }
    }

    // ---- phase 2: hh = [rh | o] @ Wh  (M=32, N=256, K=512); wave w -> out cols w*64.. ----
    const __bf16* wh = WT + (long)(14 + g) * 131072;
    const __bf16* b2base = wh + (long)(w * 64 + l15) * 512 + q * 8;
    auto loadB2 = [&](bf16x8 (&d)[4], int s) {
#pragma unroll
        for (int nt = 0; nt < 4; nt++)
            d[nt] = *(const bf16x8*)(b2base + nt * 8192 + s * 32);
    };
    f32x4 acc2[2][4] = {};
    auto step2 = [&](bf16x8 (&cu)[4], int s) {
        bf16x8 af[2];
#pragma unroll
        for (int mt = 0; mt < 2; mt++) {
            int off = (s < 8) ? (RHB + (s * 2 + mt) * 512) : (((s - 8) * 2 + mt) * 512);
            af[mt] = *(const bf16x8*)(&sm[off + q * 128 + l15 * 8]);
        }
#pragma unroll
        for (int mt = 0; mt < 2; mt++)
#pragma unroll
            for (int nt = 0; nt < 4; nt++)
                acc2[mt][nt] = __builtin_amdgcn_mfma_f32_16x16x32_bf16(af[mt], cu[nt], acc2[mt][nt], 0, 0, 0);
        if (s + 3 < 16) loadB2(cu, s + 3);
    };

    bf16x8 cc0[4], cc1[4], cc2v[4];
    loadB2(cc0, 0); loadB2(cc1, 1); loadB2(cc2v, 2);
    __syncthreads();                 // RH/ZB writes visible
#pragma unroll
    for (int s = 0; s < 16; s += 3) {
        step2(cc0, s);
        if (s + 1 < 16) step2(cc1, s + 1);
        if (s + 2 < 16) step2(cc2v, s + 2);
    }

    // ---- GRU epilogue: out = (1-z)*h + z*tanh(hh) ----
    float* og = outp + (long)g * ELEMS;
#pragma unroll
    for (int mt = 0; mt < 2; mt++)
#pragma unroll
        for (int nt = 0; nt < 4; nt++)
#pragma unroll
            for (int j = 0; j < 4; j++) {
                int row = mt * 16 + q * 4 + j;
                int col = w * 64 + nt * 16 + l15;
                float zz = (float)sm[ZBB + row * 256 + col];
                float e = __expf(2.f * acc2[mt][nt][j]);
                float th = 1.f - 2.f * __builtin_amdgcn_rcpf(e + 1.f);
                float hv = hpg[(long)(m0 + row) * 256 + col];
                og[(long)(m0 + row) * 256 + col] = (1.f - zz) * hv + zz * th;
            }
}

// ---------------- msh + sim + com ----------------
__global__ __launch_bounds__(256, 1)
void msh_kernel(MshA ma) {
    int z = blockIdx.z;
    bool tri = (z == 3);
    int b = blockIdx.x;
    int h0 = blockIdx.y * 64;
    int lane = threadIdx.x & 63;
    int w = __builtin_amdgcn_readfirstlane(threadIdx.x >> 6);
    long base = (long)b * N_ * H_ + h0 + lane;
    const __bf16* pa = ma.oa[z] + base;
    const __bf16* pb = ma.ob[z] + base;
    const __bf16* pc = ma.oc[z] + base;
    float av[N_], bv[N_], cv[N_];
#pragma unroll
    for (int n = 0; n < N_; n++) {
        av[n] = (float)pa[n * H_];
        bv[n] = (float)pb[n * H_];
    }
    if (tri) {
#pragma unroll
        for (int n = 0; n < N_; n++) cv[n] = (float)pc[n * H_];
    }
    const float* S = ma.S[z];
    __bf16* com = ma.com + (long)z * ELEMS + base;
    float lsum = 0.f;
    for (int mm = w; mm < N_; mm += 4) {        // mm wave-uniform
        float a = 0.f, bb = 0.f, cc = 0.f;
#pragma unroll
        for (int n = 0; n < N_; n++) {
            float s = S[n * N_ + mm];           // uniform -> s_load
            a += av[n] * s;
            bb += bv[n] * s;
            if (tri) cc += cv[n] * s;
        }
        if (tri) {
            com[(long)mm * H_] = (__bf16)((a + bb + cc) * (1.f/3.f));
            float d1 = a - bb, d2 = a - cc, d3 = bb - cc;
            lsum += d1*d1 + d2*d2 + d3*d3;
        } else {
            com[(long)mm * H_] = (__bf16)(0.5f * (a + bb));
            float d = a - bb;
            lsum += d * d;
        }
    }
    for (int off = 32; off > 0; off >>= 1) lsum += __shfl_down(lsum, off);
    __shared__ float wred[4];
    if (lane == 0) wred[w] = lsum;
    __syncthreads();
    if (threadIdx.x == 0) atomicAdd(ma.accs + z, wred[0] + wred[1] + wred[2] + wred[3]);
}

// ---------------- finalize sims ----------------
__global__ void fin_kernel(const float* __restrict__ accs, float* __restrict__ outp) {
    if (threadIdx.x == 0) {
        float inv = 1.f / 2293760.f;
        outp[0] = accs[0] * inv;
        outp[1] = accs[1] * inv;
        outp[2] = accs[2] * inv;
        outp[3] = accs[3] * inv;
    }
}

extern "C" void kernel_launch(void* const* d_in, const int* in_sizes, int n_in,
                              void* d_out, int out_size, void* d_ws, size_t ws_size,
                              hipStream_t stream) {
    const float* const* in = (const float* const*)d_in;
    float* out = (float*)d_out;
    char* ws = (char*)d_ws;

    size_t off = 0;
    auto alloc = [&](size_t bytes) { size_t o = off; off += (bytes + 255) & ~(size_t)255; return o; };
    float*  A12   = (float*)(ws + alloc(12*N_*N_*4));
    float*  A12sq = (float*)(ws + alloc(12*N_*N_*4));
    __bf16* WcT   = (__bf16*)(ws + alloc((size_t)12*256*128*2));
    __bf16* WT    = (__bf16*)(ws + alloc((size_t)21*256*512*2));
    float*  accs  = (float*)(ws + alloc(256));
    __bf16* gout  = (__bf16*)(ws + alloc((size_t)12*ELEMS*2));
    __bf16* com   = (__bf16*)(ws + alloc((size_t)4*ELEMS*2));
    __bf16* hbf   = (__bf16*)(ws + alloc((size_t)7*ELEMS*2));
    __bf16* xAc   = (__bf16*)(ws + alloc((size_t)12*ROWS*128*2));

    XPtrs xp;
    for (int i = 0; i < 12; i++) xp.p[i] = in[i];
    HPtrs hp;
    for (int i = 0; i < 7; i++) hp.p[i] = in[15 + i];

    // merged prep + wc + wt + hcast
    pre_kernel<<<17917, 256, 0, stream>>>(in[12], in[13], in[14], A12, A12sq,
                                          in[27], in[26], in[28], in[29],
                                          out + 7L*ELEMS + 4, accs,
                                          in[22], in[23], in[24], in[25], WcT,
                                          in[30], in[31], in[32], WT,
                                          hp, hbf);
    xa_kernel<<<dim3(12, 128), 256, 0, stream>>>(xp, A12, A12sq, xAc);

    // GCN: gout[r] = relu(xA1@W1) + relu(xA2@W2)  (ACT=4 split-relu at K/2=64)
    {
        GB gb{};
        for (int z = 0; z < 12; z++) { gb.a0[z] = xAc + (long)z*ROWS*128; gb.a1[z] = gb.a0[z]; }
        gemm_bf16<4><<<dim3(2, 70, 12), 256, 0, stream>>>(
            gb, 128, 128, 128, 128,
            WcT, WcT, 256, 128, 32768L,
            gout, 256, ELEMS, (const __bf16*)nullptr, 0L);
    }

    // msh + sim + com (4 batched in z)
    {
        MshA ma{};
        ma.oa[0] = gout + 3L*ELEMS; ma.ob[0] = gout + 4L*ELEMS; ma.oc[0] = ma.oa[0];
        ma.oa[1] = gout + 5L*ELEMS; ma.ob[1] = gout + 6L*ELEMS; ma.oc[1] = ma.oa[1];
        ma.oa[2] = gout + 7L*ELEMS; ma.ob[2] = gout + 8L*ELEMS; ma.oc[2] = ma.oa[2];
        ma.oa[3] = gout + 9L*ELEMS; ma.ob[3] = gout + 10L*ELEMS; ma.oc[3] = gout + 11L*ELEMS;
        ma.S[0] = in[26]; ma.S[1] = in[27]; ma.S[2] = in[28]; ma.S[3] = in[29];
        ma.com = com; ma.accs = accs;
        msh_kernel<<<dim3(256, 4, 4), 256, 0, stream>>>(ma);
    }

    fin_kernel<<<1, 64, 0, stream>>>(accs, out + 7L*ELEMS);

    // Fused GRU v3: split into 2 launches (visibility) with XCD-chunked swizzle
    {
        GB gb{};
        for (int g = 0; g < 7; g++) {
            gb.a0[g] = (g < 3) ? gout + (long)g*ELEMS : com + (long)(g - 3)*ELEMS;
            gb.a1[g] = hbf + (long)g*ELEMS;
            gb.hp[g] = in[15 + g];
        }
        gru_fused<<<280 * 4, 256, 0, stream>>>(gb, WT, out, 0);
        gru_fused<<<280 * 3, 256, 0, stream>>>(gb, WT, out, 4);
    }
}

// Round 5
// 484.307 us; speedup vs baseline: 1.2851x; 1.1526x over previous
//
#include <hip/hip_runtime.h>
#include <math.h>

// Problem constants
#define B_    256
#define N_    35
#define I_    64
#define H_    256
#define ROWS  8960            // B_*N_
#define ELEMS 2293760L        // ROWS*H_

typedef __bf16 bf16x8 __attribute__((ext_vector_type(8)));
typedef float f32x4 __attribute__((ext_vector_type(4)));

struct XPtrs { const float* p[12]; };
struct HPtrs { const float* p[7]; };
struct GB    { const __bf16* a0[12]; const __bf16* a1[12]; const float* hp[12]; };
struct MshA  { const __bf16* oa[4]; const __bf16* ob[4]; const __bf16* oc[4];
               const float* S[4]; __bf16* com; float* accs; };

#define GLOAD_LDS16(g, l) __builtin_amdgcn_global_load_lds( \
    (const __attribute__((address_space(1))) unsigned int*)(g), \
    (__attribute__((address_space(3))) unsigned int*)(l), 16, 0, 0)

// ---------------- merged pre-work:
//   blk 0..23    compose adjacencies
//   blk 24..27   L1 norms
//   blk 28       zero accs
//   blk 29..1564 wc (GCN basis weights)
//   blk 1565..2236 wt (GRU weight transpose)
//   blk 2237..17916 hcast (hidden fp32 -> bf16)
__global__ void pre_kernel(const float* __restrict__ As_, const float* __restrict__ Af_,
                           const float* __restrict__ At_, float* __restrict__ A12,
                           float* __restrict__ A12sq,
                           const float* __restrict__ S0, const float* __restrict__ S1,
                           const float* __restrict__ S2, const float* __restrict__ S3,
                           float* __restrict__ l1out, float* __restrict__ accs,
                           const float* __restrict__ V1, const float* __restrict__ c1,
                           const float* __restrict__ V2, const float* __restrict__ c2,
                           __bf16* __restrict__ WcT,
                           const float* __restrict__ Wr, const float* __restrict__ Wz,
                           const float* __restrict__ Wh, __bf16* __restrict__ WT,
                           HPtrs hp, __bf16* __restrict__ hbf) {
    __shared__ float shf[64 * 65];        // 16.6 KB, reused by prep and wt roles
    int blk = blockIdx.x;
    int tid = threadIdx.x;

    if (blk >= 2237) {                    // ---- hcast role ----
        int t = blk - 2237;               // 0..15679
        int gg = t / 2240;
        int bx = t - gg * 2240;
        long idx = ((long)bx * 256 + tid) * 4;
        float4 v = *(const float4*)(hp.p[gg] + idx);
        __bf16* o = hbf + (long)gg * ELEMS + idx;
        o[0] = (__bf16)v.x; o[1] = (__bf16)v.y; o[2] = (__bf16)v.z; o[3] = (__bf16)v.w;
        return;
    }
    if (blk >= 1565) {                    // ---- wt role: GRU weight transpose ----
        int t = blk - 1565;               // 0..671
        int z = t >> 5;                   // 0..20
        int rem = t & 31;
        int bx = rem & 3, by = rem >> 2;
        int mat = z / 7, gg = z % 7;
        const float* srcs[3] = {Wr, Wz, Wh};
        const float* src = srcs[mat] + (long)gg * 512 * 256;
        __bf16* dst = WT + ((long)mat * 7 + gg) * 256 * 512;
        int n0 = bx * 64;
        int k0 = by * 64;
        float (*T)[65] = (float(*)[65])shf;
        int c = tid & 63, r0 = tid >> 6;
        for (int r = r0; r < 64; r += 4)
            T[r][c] = src[(long)(k0 + r) * 256 + n0 + c];
        __syncthreads();
        for (int n = r0; n < 64; n += 4)
            dst[(long)(n0 + n) * 512 + k0 + c] = (__bf16)T[c][n];
        return;
    }
    if (blk >= 29) {                      // ---- wc role ----
        int idx = (blk - 29) * 256 + tid;
        int k = idx & 127;
        int o = (idx >> 7) & 255;
        int r = idx >> 15;
        float acc = 0.f;
        if (k < 64) {
            for (int bb = 0; bb < 4; bb++) acc += c1[r*4+bb] * V1[((long)bb*64 + k)*256 + o];
        } else {
            int kk = k - 64;
            for (int bb = 0; bb < 4; bb++) acc += c2[r*4+bb] * V2[((long)bb*64 + kk)*256 + o];
        }
        WcT[idx] = (__bf16)acc;
        return;
    }
    if (blk >= 28) {
        if (tid < 8) accs[tid] = 0.f;
        return;
    }
    if (blk >= 24) {                      // ---- L1 norms ----
        const float* mats[4] = {S0, S1, S2, S3};
        const float* S = mats[blk - 24];
        float s = 0.f;
        for (int i = tid; i < N_ * N_; i += 256) s += fabsf(S[i]);
        for (int off = 32; off > 0; off >>= 1) s += __shfl_down(s, off);
        __shared__ float wr[4];
        if ((tid & 63) == 0) wr[tid >> 6] = s;
        __syncthreads();
        if (tid == 0) l1out[blk - 24] = wr[0] + wr[1] + wr[2] + wr[3];
        return;
    }
    // ---- compose adjacencies ----
    int v = blk / 12, r = blk % 12;
    float (*M)[N_ * N_] = (float(*)[N_ * N_])shf;
    for (int i = tid; i < N_ * N_; i += 256) {
        float a = As_[i], f = Af_[i], t = At_[i];
        if (v) { a *= a; f *= f; t *= t; }
        M[0][i] = a; M[1][i] = f; M[2][i] = t;
    }
    __syncthreads();
    const int kind[12] = {0,0,0, 1,1,1,1,1,1, 2,2,2};
    const int ia[12]   = {0,1,2, 0,1,0,2,1,2, 0,0,2};
    const int ib[12]   = {0,1,2, 1,0,2,0,2,1, 1,2,0};
    const int ic[12]   = {0,0,0, 0,0,0,0,0,0, 2,1,1};
    const float* Ma = M[ia[r]];
    const float* Mb = M[ib[r]];
    const float* Mc = M[ic[r]];
    float* dst = (v ? A12sq : A12) + r * N_ * N_;
    for (int i = tid; i < N_ * N_; i += 256) {
        int m = i / N_, n = i % N_;
        float acc;
        if (kind[r] == 0) {
            acc = Ma[i];
        } else if (kind[r] == 1) {
            acc = 0.f;
            for (int p = 0; p < N_; p++) acc += Ma[m*N_+p] * Mb[p*N_+n];
        } else {
            acc = 0.f;
            for (int p = 0; p < N_; p++) {
                float t = 0.f;
                for (int q = 0; q < N_; q++) t += Mb[p*N_+q] * Mc[q*N_+n];
                acc += Ma[m*N_+p] * t;
            }
        }
        dst[i] = acc;
    }
}

// ---------------- xA fold ----------------
__global__ __launch_bounds__(256)
void xa_kernel(XPtrs xp, const float* __restrict__ A12, const float* __restrict__ A12sq,
               __bf16* __restrict__ xAc) {
    int r = blockIdx.x;
    int w = __builtin_amdgcn_readfirstlane(threadIdx.x >> 6);
    int v = w & 1, bl = w >> 1;
    int lane = threadIdx.x & 63;
    int b = blockIdx.y * 2 + bl;
    const float* x = xp.p[r] + (long)b * (N_ * I_);
    const float* As = (v ? A12sq : A12) + r * (N_ * N_);
    float xv[N_];
#pragma unroll
    for (int n = 0; n < N_; n++) xv[n] = x[n * I_ + lane];
    float acc[N_];
#pragma unroll
    for (int m = 0; m < N_; m++) acc[m] = 0.f;
#pragma unroll
    for (int n = 0; n < N_; n++) {
#pragma unroll
        for (int m = 0; m < N_; m++) acc[m] += As[m * N_ + n] * xv[n];
    }
    long obase = ((long)r * ROWS + (long)b * N_) * 128 + v * 64 + lane;
#pragma unroll
    for (int m = 0; m < N_; m++) xAc[obase + (long)m * 128] = (__bf16)acc[m];
}

// ---------------- bf16 MFMA GEMM (GCN), 128x128 tile, conflict-free chunked LDS ----
template<int ACT>
__global__ __launch_bounds__(256)
void gemm_bf16(GB gb, int K0, int K, int lda0, int lda1,
               const __bf16* __restrict__ B0, const __bf16* __restrict__ B1,
               int N0, int ldb, long bstr,
               void* __restrict__ Cp, int ldc, long cstr,
               const __bf16* __restrict__ Zb, long zstr) {
    int bz = blockIdx.z;
    int n0 = blockIdx.x * 128;
    int m0 = blockIdx.y * 128;
    const __bf16* a0 = gb.a0[bz];
    const __bf16* a1 = gb.a1[bz];
    const __bf16* bbase = ((n0 < N0) ? B0 : B1) + bz * bstr;
    int nloc = (n0 < N0) ? n0 : (n0 - N0);
    __shared__ __bf16 As[2][8 * 512];
    __shared__ __bf16 Bs[2][8 * 512];
    int tid = threadIdx.x;
    int lane = tid & 63;
    int w = tid >> 6;
    int wm = (w & 1) * 64, wn = (w >> 1) * 64;
    int l15 = lane & 15, q = lane >> 4;
    int kq8 = q * 8;
    int ca = (w & 1) * 4;
    int cb = (w >> 1) * 4;
    f32x4 acc[4][4] = {};
    f32x4 accA[4][4];
    int ksplit = K >> 1;

    auto stage = [&](int buf, int kt2) {
        const __bf16* aseg; int kk; int lda;
        if (kt2 < K0) { aseg = a0; kk = kt2; lda = lda0; }
        else          { aseg = a1; kk = kt2 - K0; lda = lda1; }
        GLOAD_LDS16(aseg + (long)(m0 + w * 16 + l15) * lda + kk + kq8,      &As[buf][w * 512]);
        GLOAD_LDS16(aseg + (long)(m0 + 64 + w * 16 + l15) * lda + kk + kq8, &As[buf][(4 + w) * 512]);
        GLOAD_LDS16(bbase + (long)(nloc + w * 16 + l15) * ldb + kt2 + kq8,      &Bs[buf][w * 512]);
        GLOAD_LDS16(bbase + (long)(nloc + 64 + w * 16 + l15) * ldb + kt2 + kq8, &Bs[buf][(4 + w) * 512]);
    };

    stage(0, 0);
    int cur = 0;
    for (int kt = 0; kt < K; kt += 32) {
        __syncthreads();
        if (kt + 32 < K) stage(cur ^ 1, kt + 32);
        const __bf16* Ac = As[cur];
        const __bf16* Bc = Bs[cur];
        bf16x8 af[4], bfr[4];
#pragma unroll
        for (int mt = 0; mt < 4; mt++) af[mt]  = *(const bf16x8*)(Ac + (ca + mt) * 512 + q * 128 + l15 * 8);
#pragma unroll
        for (int nt = 0; nt < 4; nt++) bfr[nt] = *(const bf16x8*)(Bc + (cb + nt) * 512 + q * 128 + l15 * 8);
#pragma unroll
        for (int mt = 0; mt < 4; mt++)
#pragma unroll
            for (int nt = 0; nt < 4; nt++)
                acc[mt][nt] = __builtin_amdgcn_mfma_f32_16x16x32_bf16(af[mt], bfr[nt], acc[mt][nt], 0, 0, 0);
        if (ACT == 4 && (kt + 32) == ksplit) {
#pragma unroll
            for (int mt = 0; mt < 4; mt++)
#pragma unroll
                for (int nt = 0; nt < 4; nt++)
#pragma unroll
                    for (int r = 0; r < 4; r++) {
                        accA[mt][nt][r] = fmaxf(acc[mt][nt][r], 0.f);
                        acc[mt][nt][r] = 0.f;
                    }
        }
        cur ^= 1;
    }

#pragma unroll
    for (int mt = 0; mt < 4; mt++) {
#pragma unroll
        for (int nt = 0; nt < 4; nt++) {
#pragma unroll
            for (int r = 0; r < 4; r++) {
                long row = m0 + wm + mt*16 + q*4 + r;
                int col  = n0 + wn + nt*16 + l15;
                float vv = acc[mt][nt][r];
                ((__bf16*)Cp)[bz*cstr + row * ldc + col] = (__bf16)(accA[mt][nt][r] + fmaxf(vv, 0.f));
            }
        }
    }
}

// ---------------- fused GRU v5: 64-row x 512-col tile, 8 waves, LDS-staged A AND B ----
// m97 structure: global_load_lds staging (0 VGPR cost), chunked conflict-free layout,
// double-buffered, 1 barrier per K-step. Phase 1: gates (16 steps). Epilogue1 writes
// RH (chunked, phase-2 fragment layout) + ZB to LDS. Phase 2: hh (16 steps; k<256
// A from RH, k>=256 A restaged from o). GRU epilogue to fp32 out.
// LDS map (bf16 elems): As[2][4*512] @0, Bs[2][32*512] @4096, RH @36864, ZB @53248.
#define AS0v 0
#define AS1v 2048
#define BS0v 4096
#define BS1v 20480
#define RHBv 36864
#define ZBBv 53248
__global__ __launch_bounds__(512, 2)
void gru_fused(GB gb, const __bf16* __restrict__ WT, float* __restrict__ outp) {
    __shared__ __bf16 sm[69632];     // 136 KB -> 1 block/CU
    int g = blockIdx.y;
    int m0 = blockIdx.x * 64;
    int tid = threadIdx.x;
    int lane = tid & 63;
    int w = __builtin_amdgcn_readfirstlane(tid >> 6);   // 0..7
    int l15 = lane & 15, q = lane >> 4;
    int kq8 = q * 8;
    const __bf16* __restrict__ ob  = gb.a0[g];   // o rows [ROWS x 256] bf16
    const __bf16* __restrict__ hb  = gb.a1[g];   // h rows bf16
    const float*  __restrict__ hpg = gb.hp[g];   // h fp32 (final epilogue only)
    const __bf16* wr_g = WT + (long)g * 131072;
    const __bf16* wz_g = WT + (long)(7 + g) * 131072;
    const __bf16* wh_g = WT + (long)(14 + g) * 131072;

    // ---- phase-1 staging: B = [Wr|Wz] 32 chunks (4/wave), A = [o|h] 4 chunks (waves 0-3) ----
    auto stage1 = [&](int buf, int kt) {
        int bs = buf ? BS1v : BS0v;
#pragma unroll
        for (int i = 0; i < 4; i++) {
            int c = w * 4 + i;                       // 0..31 -> gate cols 16c..16c+15
            const __bf16* bsrc = (c < 16) ? wr_g : wz_g;
            int colloc = (c < 16) ? c * 16 : (c * 16 - 256);
            GLOAD_LDS16(bsrc + (long)(colloc + l15) * 512 + kt + kq8, &sm[bs + c * 512]);
        }
        if (w < 4) {
            const __bf16* asrc = (kt < 256) ? ob : hb;
            int kk = (kt < 256) ? kt : kt - 256;
            GLOAD_LDS16(asrc + (long)(m0 + w * 16 + l15) * 256 + kk + kq8,
                        &sm[(buf ? AS1v : AS0v) + w * 512]);
        }
    };

    f32x4 acc[4][4] = {};
    stage1(0, 0);
    int cur = 0;
    for (int s = 0; s < 16; s++) {
        __syncthreads();                 // stage(cur) landed; prev reads of cur^1 done
        if (s + 1 < 16) stage1(cur ^ 1, (s + 1) * 32);
        int as = cur ? AS1v : AS0v;
        int bs = cur ? BS1v : BS0v;
        bf16x8 af[4], bfr[4];
#pragma unroll
        for (int mt = 0; mt < 4; mt++)
            af[mt] = *(const bf16x8*)&sm[as + mt * 512 + q * 128 + l15 * 8];
#pragma unroll
        for (int nt = 0; nt < 4; nt++)
            bfr[nt] = *(const bf16x8*)&sm[bs + (w * 4 + nt) * 512 + q * 128 + l15 * 8];
#pragma unroll
        for (int mt = 0; mt < 4; mt++)
#pragma unroll
            for (int nt = 0; nt < 4; nt++)
                acc[mt][nt] = __builtin_amdgcn_mfma_f32_16x16x32_bf16(af[mt], bfr[nt], acc[mt][nt], 0, 0, 0);
        cur ^= 1;
    }

    // ---- phase-2 staging: B = Wh 16 chunks (2/wave); A (s>=8) = o 4 chunks (waves 4-7) ----
    auto stage2 = [&](int buf, int s) {
        int bs = buf ? BS1v : BS0v;
#pragma unroll
        for (int i = 0; i < 2; i++) {
            int c = w * 2 + i;                       // 0..15 -> out cols 16c..
            GLOAD_LDS16(wh_g + (long)(c * 16 + l15) * 512 + s * 32 + kq8, &sm[bs + c * 512]);
        }
        if (s >= 8 && w >= 4) {
            int mt = w - 4;
            GLOAD_LDS16(ob + (long)(m0 + mt * 16 + l15) * 256 + (s - 8) * 32 + kq8,
                        &sm[(buf ? AS1v : AS0v) + mt * 512]);
        }
    };
    stage2(0, 0);    // overlap with epilogue 1 (Bs[0] free: last read at step 14)

    // ---- epilogue 1: waves 0-3 (r cols 0..255) -> RH chunked; waves 4-7 (z) -> ZB ----
    if (w < 4) {
#pragma unroll
        for (int mt = 0; mt < 4; mt++)
#pragma unroll
            for (int nt = 0; nt < 4; nt++)
#pragma unroll
                for (int j = 0; j < 4; j++) {
                    int row = mt * 16 + q * 4 + j;
                    int colg = w * 64 + nt * 16 + l15;
                    float rv = __builtin_amdgcn_rcpf(1.f + __expf(-acc[mt][nt][j]));
                    float hv = (float)hb[(long)(m0 + row) * 256 + colg];
                    // RH chunk (kgrp = colg>>5 = w*2+(nt>>1), rowgrp = mt); within:
                    // q' = (colg&31)>>3, l15' = row&15, e = colg&7
                    int rhoff = RHBv + ((w * 2 + (nt >> 1)) * 4 + mt) * 512
                              + ((nt * 2 + (l15 >> 3)) & 3) * 128 + (q * 4 + j) * 8 + (l15 & 7);
                    sm[rhoff] = (__bf16)(rv * hv);
                }
    } else {
        int w4 = w - 4;
#pragma unroll
        for (int mt = 0; mt < 4; mt++)
#pragma unroll
            for (int nt = 0; nt < 4; nt++)
#pragma unroll
                for (int j = 0; j < 4; j++) {
                    int row = mt * 16 + q * 4 + j;
                    int colp = w4 * 64 + nt * 16 + l15;
                    float zv = __builtin_amdgcn_rcpf(1.f + __expf(-acc[mt][nt][j]));
                    sm[ZBBv + row * 256 + colp] = (__bf16)zv;
                }
    }

    // ---- phase 2: hh = [rh | o] @ Wh  (64 x 256, K=512); wave w -> cols w*32.. ----
    f32x4 acc2[4][2] = {};
    cur = 0;
    for (int s = 0; s < 16; s++) {
        __syncthreads();                 // stage2(cur) landed; RH/ZB visible (first iter)
        if (s + 1 < 16) stage2(cur ^ 1, s + 1);
        int as = cur ? AS1v : AS0v;
        int bs = cur ? BS1v : BS0v;
        bf16x8 a2[4], b2[2];
#pragma unroll
        for (int mt = 0; mt < 4; mt++)
            a2[mt] = (s < 8)
                ? *(const bf16x8*)&sm[RHBv + (s * 4 + mt) * 512 + q * 128 + l15 * 8]
                : *(const bf16x8*)&sm[as + mt * 512 + q * 128 + l15 * 8];
#pragma unroll
        for (int nt = 0; nt < 2; nt++)
            b2[nt] = *(const bf16x8*)&sm[bs + (w * 2 + nt) * 512 + q * 128 + l15 * 8];
#pragma unroll
        for (int mt = 0; mt < 4; mt++)
#pragma unroll
            for (int nt = 0; nt < 2; nt++)
                acc2[mt][nt] = __builtin_amdgcn_mfma_f32_16x16x32_bf16(a2[mt], b2[nt], acc2[mt][nt], 0, 0, 0);
        cur ^= 1;
    }

    // ---- GRU epilogue: out = (1-z)*h + z*tanh(hh) ----
    float* og = outp + (long)g * ELEMS;
#pragma unroll
    for (int mt = 0; mt < 4; mt++)
#pragma unroll
        for (int nt = 0; nt < 2; nt++)
#pragma unroll
            for (int j = 0; j < 4; j++) {
                int row = mt * 16 + q * 4 + j;
                int col = w * 32 + nt * 16 + l15;
                float zz = (float)sm[ZBBv + row * 256 + col];
                float e = __expf(2.f * acc2[mt][nt][j]);
                float th = 1.f - 2.f * __builtin_amdgcn_rcpf(e + 1.f);
                float hv = hpg[(long)(m0 + row) * 256 + col];
                og[(long)(m0 + row) * 256 + col] = (1.f - zz) * hv + zz * th;
            }
}

// ---------------- msh + sim + com ----------------
__global__ __launch_bounds__(256, 1)
void msh_kernel(MshA ma) {
    int z = blockIdx.z;
    bool tri = (z == 3);
    int b = blockIdx.x;
    int h0 = blockIdx.y * 64;
    int lane = threadIdx.x & 63;
    int w = __builtin_amdgcn_readfirstlane(threadIdx.x >> 6);
    long base = (long)b * N_ * H_ + h0 + lane;
    const __bf16* pa = ma.oa[z] + base;
    const __bf16* pb = ma.ob[z] + base;
    const __bf16* pc = ma.oc[z] + base;
    float av[N_], bv[N_], cv[N_];
#pragma unroll
    for (int n = 0; n < N_; n++) {
        av[n] = (float)pa[n * H_];
        bv[n] = (float)pb[n * H_];
    }
    if (tri) {
#pragma unroll
        for (int n = 0; n < N_; n++) cv[n] = (float)pc[n * H_];
    }
    const float* S = ma.S[z];
    __bf16* com = ma.com + (long)z * ELEMS + base;
    float lsum = 0.f;
    for (int mm = w; mm < N_; mm += 4) {        // mm wave-uniform
        float a = 0.f, bb = 0.f, cc = 0.f;
#pragma unroll
        for (int n = 0; n < N_; n++) {
            float s = S[n * N_ + mm];           // uniform -> s_load
            a += av[n] * s;
            bb += bv[n] * s;
            if (tri) cc += cv[n] * s;
        }
        if (tri) {
            com[(long)mm * H_] = (__bf16)((a + bb + cc) * (1.f/3.f));
            float d1 = a - bb, d2 = a - cc, d3 = bb - cc;
            lsum += d1*d1 + d2*d2 + d3*d3;
        } else {
            com[(long)mm * H_] = (__bf16)(0.5f * (a + bb));
            float d = a - bb;
            lsum += d * d;
        }
    }
    for (int off = 32; off > 0; off >>= 1) lsum += __shfl_down(lsum, off);
    __shared__ float wred[4];
    if (lane == 0) wred[w] = lsum;
    __syncthreads();
    if (threadIdx.x == 0) atomicAdd(ma.accs + z, wred[0] + wred[1] + wred[2] + wred[3]);
}

// ---------------- finalize sims ----------------
__global__ void fin_kernel(const float* __restrict__ accs, float* __restrict__ outp) {
    if (threadIdx.x == 0) {
        float inv = 1.f / 2293760.f;
        outp[0] = accs[0] * inv;
        outp[1] = accs[1] * inv;
        outp[2] = accs[2] * inv;
        outp[3] = accs[3] * inv;
    }
}

extern "C" void kernel_launch(void* const* d_in, const int* in_sizes, int n_in,
                              void* d_out, int out_size, void* d_ws, size_t ws_size,
                              hipStream_t stream) {
    const float* const* in = (const float* const*)d_in;
    float* out = (float*)d_out;
    char* ws = (char*)d_ws;

    size_t off = 0;
    auto alloc = [&](size_t bytes) { size_t o = off; off += (bytes + 255) & ~(size_t)255; return o; };
    float*  A12   = (float*)(ws + alloc(12*N_*N_*4));
    float*  A12sq = (float*)(ws + alloc(12*N_*N_*4));
    __bf16* WcT   = (__bf16*)(ws + alloc((size_t)12*256*128*2));
    __bf16* WT    = (__bf16*)(ws + alloc((size_t)21*256*512*2));
    float*  accs  = (float*)(ws + alloc(256));
    __bf16* gout  = (__bf16*)(ws + alloc((size_t)12*ELEMS*2));
    __bf16* com   = (__bf16*)(ws + alloc((size_t)4*ELEMS*2));
    __bf16* hbf   = (__bf16*)(ws + alloc((size_t)7*ELEMS*2));
    __bf16* xAc   = (__bf16*)(ws + alloc((size_t)12*ROWS*128*2));

    XPtrs xp;
    for (int i = 0; i < 12; i++) xp.p[i] = in[i];
    HPtrs hp;
    for (int i = 0; i < 7; i++) hp.p[i] = in[15 + i];

    // merged prep + wc + wt + hcast
    pre_kernel<<<17917, 256, 0, stream>>>(in[12], in[13], in[14], A12, A12sq,
                                          in[27], in[26], in[28], in[29],
                                          out + 7L*ELEMS + 4, accs,
                                          in[22], in[23], in[24], in[25], WcT,
                                          in[30], in[31], in[32], WT,
                                          hp, hbf);
    xa_kernel<<<dim3(12, 128), 256, 0, stream>>>(xp, A12, A12sq, xAc);

    // GCN: gout[r] = relu(xA1@W1) + relu(xA2@W2)  (ACT=4 split-relu at K/2=64)
    {
        GB gb{};
        for (int z = 0; z < 12; z++) { gb.a0[z] = xAc + (long)z*ROWS*128; gb.a1[z] = gb.a0[z]; }
        gemm_bf16<4><<<dim3(2, 70, 12), 256, 0, stream>>>(
            gb, 128, 128, 128, 128,
            WcT, WcT, 256, 128, 32768L,
            gout, 256, ELEMS, (const __bf16*)nullptr, 0L);
    }

    // msh + sim + com (4 batched in z)
    {
        MshA ma{};
        ma.oa[0] = gout + 3L*ELEMS; ma.ob[0] = gout + 4L*ELEMS; ma.oc[0] = ma.oa[0];
        ma.oa[1] = gout + 5L*ELEMS; ma.ob[1] = gout + 6L*ELEMS; ma.oc[1] = ma.oa[1];
        ma.oa[2] = gout + 7L*ELEMS; ma.ob[2] = gout + 8L*ELEMS; ma.oc[2] = ma.oa[2];
        ma.oa[3] = gout + 9L*ELEMS; ma.ob[3] = gout + 10L*ELEMS; ma.oc[3] = gout + 11L*ELEMS;
        ma.S[0] = in[26]; ma.S[1] = in[27]; ma.S[2] = in[28]; ma.S[3] = in[29];
        ma.com = com; ma.accs = accs;
        msh_kernel<<<dim3(256, 4, 4), 256, 0, stream>>>(ma);
    }

    fin_kernel<<<1, 64, 0, stream>>>(accs, out + 7L*ELEMS);

    // Fused GRU v5: 64-row tiles, LDS-staged A+B, single launch
    {
        GB gb{};
        for (int g = 0; g < 7; g++) {
            gb.a0[g] = (g < 3) ? gout + (long)g*ELEMS : com + (long)(g - 3)*ELEMS;
            gb.a1[g] = hbf + (long)g*ELEMS;
            gb.hp[g] = in[15 + g];
        }
        gru_fused<<<dim3(140, 7), 512, 0, stream>>>(gb, WT, out);
    }
}

// Round 6
// 470.324 us; speedup vs baseline: 1.3233x; 1.0297x over previous
//
#include <hip/hip_runtime.h>
#include <math.h>

// Problem constants
#define B_    256
#define N_    35
#define I_    64
#define H_    256
#define ROWS  8960            // B_*N_
#define ELEMS 2293760L        // ROWS*H_

typedef __bf16 bf16x8 __attribute__((ext_vector_type(8)));
typedef float f32x4 __attribute__((ext_vector_type(4)));

struct XPtrs { const float* p[12]; };
struct HPtrs { const float* p[7]; };
struct GB    { const __bf16* a0[12]; const __bf16* a1[12]; const float* hp[12]; };
struct MshA  { const __bf16* oa[4]; const __bf16* ob[4]; const __bf16* oc[4];
               const float* S[4]; __bf16* com; float* accs; };

#define GLOAD_LDS16(g, l) __builtin_amdgcn_global_load_lds( \
    (const __attribute__((address_space(1))) unsigned int*)(g), \
    (__attribute__((address_space(3))) unsigned int*)(l), 16, 0, 0)

#define SCHED0() __builtin_amdgcn_sched_barrier(0)
#define SBAR()   __builtin_amdgcn_s_barrier()

// ---------------- merged pre-work (unchanged from r5) ----------------
__global__ void pre_kernel(const float* __restrict__ As_, const float* __restrict__ Af_,
                           const float* __restrict__ At_, float* __restrict__ A12,
                           float* __restrict__ A12sq,
                           const float* __restrict__ S0, const float* __restrict__ S1,
                           const float* __restrict__ S2, const float* __restrict__ S3,
                           float* __restrict__ l1out, float* __restrict__ accs,
                           const float* __restrict__ V1, const float* __restrict__ c1,
                           const float* __restrict__ V2, const float* __restrict__ c2,
                           __bf16* __restrict__ WcT,
                           const float* __restrict__ Wr, const float* __restrict__ Wz,
                           const float* __restrict__ Wh, __bf16* __restrict__ WT,
                           HPtrs hp, __bf16* __restrict__ hbf) {
    __shared__ float shf[64 * 65];
    int blk = blockIdx.x;
    int tid = threadIdx.x;

    if (blk >= 2237) {                    // hcast
        int t = blk - 2237;
        int gg = t / 2240;
        int bx = t - gg * 2240;
        long idx = ((long)bx * 256 + tid) * 4;
        float4 v = *(const float4*)(hp.p[gg] + idx);
        __bf16* o = hbf + (long)gg * ELEMS + idx;
        o[0] = (__bf16)v.x; o[1] = (__bf16)v.y; o[2] = (__bf16)v.z; o[3] = (__bf16)v.w;
        return;
    }
    if (blk >= 1565) {                    // wt
        int t = blk - 1565;
        int z = t >> 5;
        int rem = t & 31;
        int bx = rem & 3, by = rem >> 2;
        int mat = z / 7, gg = z % 7;
        const float* srcs[3] = {Wr, Wz, Wh};
        const float* src = srcs[mat] + (long)gg * 512 * 256;
        __bf16* dst = WT + ((long)mat * 7 + gg) * 256 * 512;
        int n0 = bx * 64;
        int k0 = by * 64;
        float (*T)[65] = (float(*)[65])shf;
        int c = tid & 63, r0 = tid >> 6;
        for (int r = r0; r < 64; r += 4)
            T[r][c] = src[(long)(k0 + r) * 256 + n0 + c];
        __syncthreads();
        for (int n = r0; n < 64; n += 4)
            dst[(long)(n0 + n) * 512 + k0 + c] = (__bf16)T[c][n];
        return;
    }
    if (blk >= 29) {                      // wc
        int idx = (blk - 29) * 256 + tid;
        int k = idx & 127;
        int o = (idx >> 7) & 255;
        int r = idx >> 15;
        float acc = 0.f;
        if (k < 64) {
            for (int bb = 0; bb < 4; bb++) acc += c1[r*4+bb] * V1[((long)bb*64 + k)*256 + o];
        } else {
            int kk = k - 64;
            for (int bb = 0; bb < 4; bb++) acc += c2[r*4+bb] * V2[((long)bb*64 + kk)*256 + o];
        }
        WcT[idx] = (__bf16)acc;
        return;
    }
    if (blk >= 28) {
        if (tid < 8) accs[tid] = 0.f;
        return;
    }
    if (blk >= 24) {                      // L1
        const float* mats[4] = {S0, S1, S2, S3};
        const float* S = mats[blk - 24];
        float s = 0.f;
        for (int i = tid; i < N_ * N_; i += 256) s += fabsf(S[i]);
        for (int off = 32; off > 0; off >>= 1) s += __shfl_down(s, off);
        __shared__ float wr[4];
        if ((tid & 63) == 0) wr[tid >> 6] = s;
        __syncthreads();
        if (tid == 0) l1out[blk - 24] = wr[0] + wr[1] + wr[2] + wr[3];
        return;
    }
    int v = blk / 12, r = blk % 12;
    float (*M)[N_ * N_] = (float(*)[N_ * N_])shf;
    for (int i = tid; i < N_ * N_; i += 256) {
        float a = As_[i], f = Af_[i], t = At_[i];
        if (v) { a *= a; f *= f; t *= t; }
        M[0][i] = a; M[1][i] = f; M[2][i] = t;
    }
    __syncthreads();
    const int kind[12] = {0,0,0, 1,1,1,1,1,1, 2,2,2};
    const int ia[12]   = {0,1,2, 0,1,0,2,1,2, 0,0,2};
    const int ib[12]   = {0,1,2, 1,0,2,0,2,1, 1,2,0};
    const int ic[12]   = {0,0,0, 0,0,0,0,0,0, 2,1,1};
    const float* Ma = M[ia[r]];
    const float* Mb = M[ib[r]];
    const float* Mc = M[ic[r]];
    float* dst = (v ? A12sq : A12) + r * N_ * N_;
    for (int i = tid; i < N_ * N_; i += 256) {
        int m = i / N_, n = i % N_;
        float acc;
        if (kind[r] == 0) {
            acc = Ma[i];
        } else if (kind[r] == 1) {
            acc = 0.f;
            for (int p = 0; p < N_; p++) acc += Ma[m*N_+p] * Mb[p*N_+n];
        } else {
            acc = 0.f;
            for (int p = 0; p < N_; p++) {
                float t = 0.f;
                for (int q = 0; q < N_; q++) t += Mb[p*N_+q] * Mc[q*N_+n];
                acc += Ma[m*N_+p] * t;
            }
        }
        dst[i] = acc;
    }
}

// ---------------- xA fold ----------------
__global__ __launch_bounds__(256)
void xa_kernel(XPtrs xp, const float* __restrict__ A12, const float* __restrict__ A12sq,
               __bf16* __restrict__ xAc) {
    int r = blockIdx.x;
    int w = __builtin_amdgcn_readfirstlane(threadIdx.x >> 6);
    int v = w & 1, bl = w >> 1;
    int lane = threadIdx.x & 63;
    int b = blockIdx.y * 2 + bl;
    const float* x = xp.p[r] + (long)b * (N_ * I_);
    const float* As = (v ? A12sq : A12) + r * (N_ * N_);
    float xv[N_];
#pragma unroll
    for (int n = 0; n < N_; n++) xv[n] = x[n * I_ + lane];
    float acc[N_];
#pragma unroll
    for (int m = 0; m < N_; m++) acc[m] = 0.f;
#pragma unroll
    for (int n = 0; n < N_; n++) {
#pragma unroll
        for (int m = 0; m < N_; m++) acc[m] += As[m * N_ + n] * xv[n];
    }
    long obase = ((long)r * ROWS + (long)b * N_) * 128 + v * 64 + lane;
#pragma unroll
    for (int m = 0; m < N_; m++) xAc[obase + (long)m * 128] = (__bf16)acc[m];
}

// ---------------- bf16 MFMA GEMM (GCN), unchanged ----------------
template<int ACT>
__global__ __launch_bounds__(256)
void gemm_bf16(GB gb, int K0, int K, int lda0, int lda1,
               const __bf16* __restrict__ B0, const __bf16* __restrict__ B1,
               int N0, int ldb, long bstr,
               void* __restrict__ Cp, int ldc, long cstr,
               const __bf16* __restrict__ Zb, long zstr) {
    int bz = blockIdx.z;
    int n0 = blockIdx.x * 128;
    int m0 = blockIdx.y * 128;
    const __bf16* a0 = gb.a0[bz];
    const __bf16* a1 = gb.a1[bz];
    const __bf16* bbase = ((n0 < N0) ? B0 : B1) + bz * bstr;
    int nloc = (n0 < N0) ? n0 : (n0 - N0);
    __shared__ __bf16 As[2][8 * 512];
    __shared__ __bf16 Bs[2][8 * 512];
    int tid = threadIdx.x;
    int lane = tid & 63;
    int w = tid >> 6;
    int wm = (w & 1) * 64, wn = (w >> 1) * 64;
    int l15 = lane & 15, q = lane >> 4;
    int kq8 = q * 8;
    int ca = (w & 1) * 4;
    int cb = (w >> 1) * 4;
    f32x4 acc[4][4] = {};
    f32x4 accA[4][4];
    int ksplit = K >> 1;

    auto stage = [&](int buf, int kt2) {
        const __bf16* aseg; int kk; int lda;
        if (kt2 < K0) { aseg = a0; kk = kt2; lda = lda0; }
        else          { aseg = a1; kk = kt2 - K0; lda = lda1; }
        GLOAD_LDS16(aseg + (long)(m0 + w * 16 + l15) * lda + kk + kq8,      &As[buf][w * 512]);
        GLOAD_LDS16(aseg + (long)(m0 + 64 + w * 16 + l15) * lda + kk + kq8, &As[buf][(4 + w) * 512]);
        GLOAD_LDS16(bbase + (long)(nloc + w * 16 + l15) * ldb + kt2 + kq8,      &Bs[buf][w * 512]);
        GLOAD_LDS16(bbase + (long)(nloc + 64 + w * 16 + l15) * ldb + kt2 + kq8, &Bs[buf][(4 + w) * 512]);
    };

    stage(0, 0);
    int cur = 0;
    for (int kt = 0; kt < K; kt += 32) {
        __syncthreads();
        if (kt + 32 < K) stage(cur ^ 1, kt + 32);
        const __bf16* Ac = As[cur];
        const __bf16* Bc = Bs[cur];
        bf16x8 af[4], bfr[4];
#pragma unroll
        for (int mt = 0; mt < 4; mt++) af[mt]  = *(const bf16x8*)(Ac + (ca + mt) * 512 + q * 128 + l15 * 8);
#pragma unroll
        for (int nt = 0; nt < 4; nt++) bfr[nt] = *(const bf16x8*)(Bc + (cb + nt) * 512 + q * 128 + l15 * 8);
#pragma unroll
        for (int mt = 0; mt < 4; mt++)
#pragma unroll
            for (int nt = 0; nt < 4; nt++)
                acc[mt][nt] = __builtin_amdgcn_mfma_f32_16x16x32_bf16(af[mt], bfr[nt], acc[mt][nt], 0, 0, 0);
        if (ACT == 4 && (kt + 32) == ksplit) {
#pragma unroll
            for (int mt = 0; mt < 4; mt++)
#pragma unroll
                for (int nt = 0; nt < 4; nt++)
#pragma unroll
                    for (int r = 0; r < 4; r++) {
                        accA[mt][nt][r] = fmaxf(acc[mt][nt][r], 0.f);
                        acc[mt][nt][r] = 0.f;
                    }
        }
        cur ^= 1;
    }

#pragma unroll
    for (int mt = 0; mt < 4; mt++) {
#pragma unroll
        for (int nt = 0; nt < 4; nt++) {
#pragma unroll
            for (int r = 0; r < 4; r++) {
                long row = m0 + wm + mt*16 + q*4 + r;
                int col  = n0 + wn + nt*16 + l15;
                float vv = acc[mt][nt][r];
                ((__bf16*)Cp)[bz*cstr + row * ldc + col] = (__bf16)(accA[mt][nt][r] + fmaxf(vv, 0.f));
            }
        }
    }
}

// ---------------- fused GRU v6: counted-vmcnt raw-barrier pipeline ----------
// 64 rows x 512 cols, 8 waves. KEY: B staging is wave-private (wave w stages exactly
// the chunks only it reads) -> B needs NO barrier, only the wave's own counted vmcnt.
// A (shared, 4KB/step) triple-buffered, staged 2 steps ahead; one raw s_barrier/step.
// Loads stay in flight ~2 compute phases (m218 counted-vmcnt mechanism).
// LDS (bf16 elems): A 3x2048 @0, B 2x16384 @6144, RH @38912, ZB @55296. 140 KB.
#define ABUF(b) (2048 * (b))
#define BBUF(b) (6144 + 16384 * (b))
#define RHB 38912
#define ZBB 55296
__global__ __launch_bounds__(512, 2)
void gru_fused(GB gb, const __bf16* __restrict__ WT, float* __restrict__ outp) {
    __shared__ __bf16 sm[71680];     // 140 KB
    int g = blockIdx.y;
    int m0 = blockIdx.x * 64;
    int tid = threadIdx.x;
    int lane = tid & 63;
    int w = __builtin_amdgcn_readfirstlane(tid >> 6);   // 0..7
    bool wlt4 = (w < 4);
    int l15 = lane & 15, q = lane >> 4;
    int kq8 = q * 8;
    const __bf16* __restrict__ ob  = gb.a0[g];
    const __bf16* __restrict__ hb  = gb.a1[g];
    const float*  __restrict__ hpg = gb.hp[g];
    const __bf16* wr_g = WT + (long)g * 131072;
    const __bf16* wz_g = WT + (long)(7 + g) * 131072;
    const __bf16* wh_g = WT + (long)(14 + g) * 131072;

    // A(t): shared 4 chunks (waves 0-3 stage chunk w). t<8 -> o, t>=8 -> h.
    auto stageA1 = [&](int t) {
        const __bf16* src = (t < 8) ? ob : hb;
        GLOAD_LDS16(src + (long)(m0 + w * 16 + l15) * 256 + (t & 7) * 32 + kq8,
                    &sm[ABUF(t % 3) + w * 512]);
    };
    // B(t): wave-private 4 chunks c = w*4..w*4+3 (gate cols 16c..16c+15).
    auto stageB1 = [&](int t) {
#pragma unroll
        for (int i = 0; i < 4; i++) {
            int c = w * 4 + i;
            const __bf16* bsrc = (c < 16) ? wr_g : wz_g;
            int colloc = (c < 16) ? c * 16 : (c * 16 - 256);
            GLOAD_LDS16(bsrc + (long)(colloc + l15) * 512 + t * 32 + kq8,
                        &sm[BBUF(t & 1) + c * 512]);
        }
    };

    // ---- prologue: A(0),B(0),A(1),B(1) (order matters for vmcnt counts) ----
    if (wlt4) stageA1(0);
    stageB1(0);
    if (wlt4) stageA1(1);
    stageB1(1);
    SCHED0();

    // ---- phase 1: gates = [o|h] @ [Wr|Wz], 16 K-steps ----
    f32x4 acc[4][4] = {};
#pragma unroll
    for (int s = 0; s < 16; s++) {
        // retire A(s),B(s); keep A(s+1),B(s+1) (+newer) in flight
        if (s == 15)      { asm volatile("s_waitcnt vmcnt(0)" ::: "memory"); }
        else if (wlt4)    { asm volatile("s_waitcnt vmcnt(5)" ::: "memory"); }
        else              { asm volatile("s_waitcnt vmcnt(4)" ::: "memory"); }
        SCHED0();
        SBAR();
        SCHED0();
        if (wlt4 && s + 2 < 16) stageA1(s + 2);
        SCHED0();
        int as_ = ABUF(s % 3);
        int bs_ = BBUF(s & 1);
        bf16x8 af[4], bfr[4];
#pragma unroll
        for (int mt = 0; mt < 4; mt++)
            af[mt] = *(const bf16x8*)&sm[as_ + mt * 512 + q * 128 + l15 * 8];
#pragma unroll
        for (int nt = 0; nt < 4; nt++)
            bfr[nt] = *(const bf16x8*)&sm[bs_ + (w * 4 + nt) * 512 + q * 128 + l15 * 8];
#pragma unroll
        for (int mt = 0; mt < 4; mt++)
#pragma unroll
            for (int nt = 0; nt < 4; nt++)
                acc[mt][nt] = __builtin_amdgcn_mfma_f32_16x16x32_bf16(af[mt], bfr[nt], acc[mt][nt], 0, 0, 0);
        SCHED0();
        if (s + 2 < 16) stageB1(s + 2);   // into buf s&1: my reads done, chunks private
        SCHED0();
    }

    // ---- phase-2 B staging (wave-private Wh chunks c = w*2, w*2+1), issue early ----
    auto stageB2 = [&](int t) {
#pragma unroll
        for (int i = 0; i < 2; i++) {
            int c = w * 2 + i;
            GLOAD_LDS16(wh_g + (long)(c * 16 + l15) * 512 + t * 32 + kq8,
                        &sm[BBUF(t & 1) + c * 512]);
        }
    };
    auto stageA2 = [&](int t) {           // t in 8..15, o restage, waves 0-3
        GLOAD_LDS16(ob + (long)(m0 + w * 16 + l15) * 256 + (t - 8) * 32 + kq8,
                    &sm[ABUF(t % 3) + w * 512]);
    };
    stageB2(0);
    stageB2(1);
    SCHED0();

    // ---- epilogue 1: waves 0-3 -> RH = sigmoid(r)*h (chunked); waves 4-7 -> ZB ----
    if (wlt4) {
#pragma unroll
        for (int mt = 0; mt < 4; mt++)
#pragma unroll
            for (int nt = 0; nt < 4; nt++)
#pragma unroll
                for (int j = 0; j < 4; j++) {
                    int row = mt * 16 + q * 4 + j;
                    int colg = w * 64 + nt * 16 + l15;
                    float rv = __builtin_amdgcn_rcpf(1.f + __expf(-acc[mt][nt][j]));
                    float hv = (float)hb[(long)(m0 + row) * 256 + colg];
                    int rhoff = RHB + ((w * 2 + (nt >> 1)) * 4 + mt) * 512
                              + ((nt * 2 + (l15 >> 3)) & 3) * 128 + (q * 4 + j) * 8 + (l15 & 7);
                    sm[rhoff] = (__bf16)(rv * hv);
                }
    } else {
        int w4 = w - 4;
#pragma unroll
        for (int mt = 0; mt < 4; mt++)
#pragma unroll
            for (int nt = 0; nt < 4; nt++)
#pragma unroll
                for (int j = 0; j < 4; j++) {
                    int row = mt * 16 + q * 4 + j;
                    int colp = w4 * 64 + nt * 16 + l15;
                    float zv = __builtin_amdgcn_rcpf(1.f + __expf(-acc[mt][nt][j]));
                    sm[ZBB + row * 256 + colp] = (__bf16)zv;
                }
    }
    asm volatile("s_waitcnt lgkmcnt(0)" ::: "memory");
    SCHED0();
    SBAR();                              // RH/ZB visible
    SCHED0();

    // ---- phase 2: hh = [rh | o] @ Wh (64x256, K=512, 16 steps) ----
    // steps 0-7: A = RH from LDS (no staging, NO barriers; B private counted-vmcnt).
    // steps 8-15: A = o restaged (shared) -> barrier per step.
    f32x4 acc2[4][2] = {};
#pragma unroll
    for (int s = 0; s < 16; s++) {
        if (s == 15)              { asm volatile("s_waitcnt vmcnt(0)" ::: "memory"); }
        else if (wlt4 && s >= 7)  { asm volatile("s_waitcnt vmcnt(3)" ::: "memory"); }
        else                      { asm volatile("s_waitcnt vmcnt(2)" ::: "memory"); }
        SCHED0();
        if (s >= 8) { SBAR(); SCHED0(); }
        if (wlt4 && s >= 6 && s + 2 < 16) stageA2(s + 2);
        SCHED0();
        int bs_ = BBUF(s & 1);
        bf16x8 a2[4], b2[2];
#pragma unroll
        for (int mt = 0; mt < 4; mt++)
            a2[mt] = (s < 8)
                ? *(const bf16x8*)&sm[RHB + (s * 4 + mt) * 512 + q * 128 + l15 * 8]
                : *(const bf16x8*)&sm[ABUF(s % 3) + mt * 512 + q * 128 + l15 * 8];
#pragma unroll
        for (int nt = 0; nt < 2; nt++)
            b2[nt] = *(const bf16x8*)&sm[bs_ + (w * 2 + nt) * 512 + q * 128 + l15 * 8];
#pragma unroll
        for (int mt = 0; mt < 4; mt++)
#pragma unroll
            for (int nt = 0; nt < 2; nt++)
                acc2[mt][nt] = __builtin_amdgcn_mfma_f32_16x16x32_bf16(a2[mt], b2[nt], acc2[mt][nt], 0, 0, 0);
        SCHED0();
        if (s + 2 < 16) stageB2(s + 2);
        SCHED0();
    }

    // ---- GRU epilogue: out = (1-z)*h + z*tanh(hh) ----
    float* og = outp + (long)g * ELEMS;
#pragma unroll
    for (int mt = 0; mt < 4; mt++)
#pragma unroll
        for (int nt = 0; nt < 2; nt++)
#pragma unroll
            for (int j = 0; j < 4; j++) {
                int row = mt * 16 + q * 4 + j;
                int col = w * 32 + nt * 16 + l15;
                float zz = (float)sm[ZBB + row * 256 + col];
                float e = __expf(2.f * acc2[mt][nt][j]);
                float th = 1.f - 2.f * __builtin_amdgcn_rcpf(e + 1.f);
                float hv = hpg[(long)(m0 + row) * 256 + col];
                og[(long)(m0 + row) * 256 + col] = (1.f - zz) * hv + zz * th;
            }
}

// ---------------- msh + sim + com ----------------
__global__ __launch_bounds__(256, 1)
void msh_kernel(MshA ma) {
    int z = blockIdx.z;
    bool tri = (z == 3);
    int b = blockIdx.x;
    int h0 = blockIdx.y * 64;
    int lane = threadIdx.x & 63;
    int w = __builtin_amdgcn_readfirstlane(threadIdx.x >> 6);
    long base = (long)b * N_ * H_ + h0 + lane;
    const __bf16* pa = ma.oa[z] + base;
    const __bf16* pb = ma.ob[z] + base;
    const __bf16* pc = ma.oc[z] + base;
    float av[N_], bv[N_], cv[N_];
#pragma unroll
    for (int n = 0; n < N_; n++) {
        av[n] = (float)pa[n * H_];
        bv[n] = (float)pb[n * H_];
    }
    if (tri) {
#pragma unroll
        for (int n = 0; n < N_; n++) cv[n] = (float)pc[n * H_];
    }
    const float* S = ma.S[z];
    __bf16* com = ma.com + (long)z * ELEMS + base;
    float lsum = 0.f;
    for (int mm = w; mm < N_; mm += 4) {
        float a = 0.f, bb = 0.f, cc = 0.f;
#pragma unroll
        for (int n = 0; n < N_; n++) {
            float s = S[n * N_ + mm];
            a += av[n] * s;
            bb += bv[n] * s;
            if (tri) cc += cv[n] * s;
        }
        if (tri) {
            com[(long)mm * H_] = (__bf16)((a + bb + cc) * (1.f/3.f));
            float d1 = a - bb, d2 = a - cc, d3 = bb - cc;
            lsum += d1*d1 + d2*d2 + d3*d3;
        } else {
            com[(long)mm * H_] = (__bf16)(0.5f * (a + bb));
            float d = a - bb;
            lsum += d * d;
        }
    }
    for (int off = 32; off > 0; off >>= 1) lsum += __shfl_down(lsum, off);
    __shared__ float wred[4];
    if (lane == 0) wred[w] = lsum;
    __syncthreads();
    if (threadIdx.x == 0) atomicAdd(ma.accs + z, wred[0] + wred[1] + wred[2] + wred[3]);
}

// ---------------- finalize sims ----------------
__global__ void fin_kernel(const float* __restrict__ accs, float* __restrict__ outp) {
    if (threadIdx.x == 0) {
        float inv = 1.f / 2293760.f;
        outp[0] = accs[0] * inv;
        outp[1] = accs[1] * inv;
        outp[2] = accs[2] * inv;
        outp[3] = accs[3] * inv;
    }
}

extern "C" void kernel_launch(void* const* d_in, const int* in_sizes, int n_in,
                              void* d_out, int out_size, void* d_ws, size_t ws_size,
                              hipStream_t stream) {
    const float* const* in = (const float* const*)d_in;
    float* out = (float*)d_out;
    char* ws = (char*)d_ws;

    size_t off = 0;
    auto alloc = [&](size_t bytes) { size_t o = off; off += (bytes + 255) & ~(size_t)255; return o; };
    float*  A12   = (float*)(ws + alloc(12*N_*N_*4));
    float*  A12sq = (float*)(ws + alloc(12*N_*N_*4));
    __bf16* WcT   = (__bf16*)(ws + alloc((size_t)12*256*128*2));
    __bf16* WT    = (__bf16*)(ws + alloc((size_t)21*256*512*2));
    float*  accs  = (float*)(ws + alloc(256));
    __bf16* gout  = (__bf16*)(ws + alloc((size_t)12*ELEMS*2));
    __bf16* com   = (__bf16*)(ws + alloc((size_t)4*ELEMS*2));
    __bf16* hbf   = (__bf16*)(ws + alloc((size_t)7*ELEMS*2));
    __bf16* xAc   = (__bf16*)(ws + alloc((size_t)12*ROWS*128*2));

    XPtrs xp;
    for (int i = 0; i < 12; i++) xp.p[i] = in[i];
    HPtrs hp;
    for (int i = 0; i < 7; i++) hp.p[i] = in[15 + i];

    pre_kernel<<<17917, 256, 0, stream>>>(in[12], in[13], in[14], A12, A12sq,
                                          in[27], in[26], in[28], in[29],
                                          out + 7L*ELEMS + 4, accs,
                                          in[22], in[23], in[24], in[25], WcT,
                                          in[30], in[31], in[32], WT,
                                          hp, hbf);
    xa_kernel<<<dim3(12, 128), 256, 0, stream>>>(xp, A12, A12sq, xAc);

    // GCN: gout[r] = relu(xA1@W1) + relu(xA2@W2)
    {
        GB gb{};
        for (int z = 0; z < 12; z++) { gb.a0[z] = xAc + (long)z*ROWS*128; gb.a1[z] = gb.a0[z]; }
        gemm_bf16<4><<<dim3(2, 70, 12), 256, 0, stream>>>(
            gb, 128, 128, 128, 128,
            WcT, WcT, 256, 128, 32768L,
            gout, 256, ELEMS, (const __bf16*)nullptr, 0L);
    }

    // msh + sim + com
    {
        MshA ma{};
        ma.oa[0] = gout + 3L*ELEMS; ma.ob[0] = gout + 4L*ELEMS; ma.oc[0] = ma.oa[0];
        ma.oa[1] = gout + 5L*ELEMS; ma.ob[1] = gout + 6L*ELEMS; ma.oc[1] = ma.oa[1];
        ma.oa[2] = gout + 7L*ELEMS; ma.ob[2] = gout + 8L*ELEMS; ma.oc[2] = ma.oa[2];
        ma.oa[3] = gout + 9L*ELEMS; ma.ob[3] = gout + 10L*ELEMS; ma.oc[3] = gout + 11L*ELEMS;
        ma.S[0] = in[26]; ma.S[1] = in[27]; ma.S[2] = in[28]; ma.S[3] = in[29];
        ma.com = com; ma.accs = accs;
        msh_kernel<<<dim3(256, 4, 4), 256, 0, stream>>>(ma);
    }

    fin_kernel<<<1, 64, 0, stream>>>(accs, out + 7L*ELEMS);

    // Fused GRU v6: counted-vmcnt raw-barrier pipeline
    {
        GB gb{};
        for (int g = 0; g < 7; g++) {
            gb.a0[g] = (g < 3) ? gout + (long)g*ELEMS : com + (long)(g - 3)*ELEMS;
            gb.a1[g] = hbf + (long)g*ELEMS;
            gb.hp[g] = in[15 + g];
        }
        gru_fused<<<dim3(140, 7), 512, 0, stream>>>(gb, WT, out);
    }
}